// Round 1
// baseline (3160.223 us; speedup 1.0000x reference)
//
#include <hip/hip_runtime.h>
#include <math.h>

#define NB 64
#define NN 197
#define DD 768
#define NH 12
#define HD_ 64
#define NT 30
#define SCALE_ 0.125f
#define KP 68   // padded LDS row stride (floats), 68*4B = 272B = 17*16B -> b128 aligned

// ---------------------------------------------------------------------------
// GEMM: C(M=12608, 768) = A @ W(768,768) + bias
// tile 64 rows x 128 cols, BK=16, 256 threads, 4x8 micro-tile
// scatter=1: write into (B, H, N, HD) layout (col tile of 128 == 2 heads)
// blockIdx.z selects (W0,b0,o0)/(W1,b1,o1)/(W2,b2,o2)
// ---------------------------------------------------------------------------
__global__ __launch_bounds__(256) void gemm_kernel(
    const float* __restrict__ A,
    const float* __restrict__ W0, const float* __restrict__ W1, const float* __restrict__ W2,
    const float* __restrict__ b0, const float* __restrict__ b1, const float* __restrict__ b2,
    float* __restrict__ o0, float* __restrict__ o1, float* __restrict__ o2,
    int scatter)
{
    const float* W = W0; const float* bias = b0; float* out = o0;
    if (blockIdx.z == 1) { W = W1; bias = b1; out = o1; }
    else if (blockIdx.z == 2) { W = W2; bias = b2; out = o2; }

    __shared__ float As[16][64];    // transposed: As[k][m]
    __shared__ float Ws[16][128];

    const int tid = threadIdx.x;
    const int m0 = blockIdx.y * 64;
    const int n0 = blockIdx.x * 128;

    const int alr = tid >> 2;            // 0..63 A-row in tile
    const int alk = (tid & 3) << 2;      // 0,4,8,12
    const int wr0 = tid >> 5;            // 0..7
    const int wc0 = (tid & 31) << 2;     // 0..124

    const int tx = tid & 15;
    const int ty = tid >> 4;

    float acc[4][8];
    #pragma unroll
    for (int r = 0; r < 4; ++r)
        #pragma unroll
        for (int u = 0; u < 8; ++u) acc[r][u] = 0.f;

    for (int kt = 0; kt < 768; kt += 16) {
        float4 av  = *(const float4*)(A + (size_t)(m0 + alr)*768 + kt + alk);
        float4 w4a = *(const float4*)(W + (size_t)(kt + wr0)*768 + n0 + wc0);
        float4 w4b = *(const float4*)(W + (size_t)(kt + wr0 + 8)*768 + n0 + wc0);
        __syncthreads();
        As[alk+0][alr] = av.x;
        As[alk+1][alr] = av.y;
        As[alk+2][alr] = av.z;
        As[alk+3][alr] = av.w;
        *(float4*)&Ws[wr0][wc0]     = w4a;
        *(float4*)&Ws[wr0+8][wc0]   = w4b;
        __syncthreads();
        #pragma unroll
        for (int kk = 0; kk < 16; ++kk) {
            float4 a4  = *(const float4*)&As[kk][ty << 2];
            float4 b4a = *(const float4*)&Ws[kk][tx << 2];
            float4 b4b = *(const float4*)&Ws[kk][(tx << 2) + 64];
            float ar[4] = {a4.x, a4.y, a4.z, a4.w};
            float br[8] = {b4a.x, b4a.y, b4a.z, b4a.w, b4b.x, b4b.y, b4b.z, b4b.w};
            #pragma unroll
            for (int r = 0; r < 4; ++r)
                #pragma unroll
                for (int u = 0; u < 8; ++u)
                    acc[r][u] += ar[r] * br[u];
        }
    }

    float4 biasA = *(const float4*)(bias + n0 + (tx << 2));
    float4 biasB = *(const float4*)(bias + n0 + 64 + (tx << 2));
    const int h0 = blockIdx.x << 1;

    #pragma unroll
    for (int r = 0; r < 4; ++r) {
        int row = m0 + (ty << 2) + r;
        float4 ra, rb;
        ra.x = acc[r][0] + biasA.x; ra.y = acc[r][1] + biasA.y;
        ra.z = acc[r][2] + biasA.z; ra.w = acc[r][3] + biasA.w;
        rb.x = acc[r][4] + biasB.x; rb.y = acc[r][5] + biasB.y;
        rb.z = acc[r][6] + biasB.z; rb.w = acc[r][7] + biasB.w;
        if (scatter) {
            int bb = row / 197;
            int nn = row - bb * 197;
            size_t base = ((size_t)(bb * NH + h0) * 197 + nn) * 64 + (tx << 2);
            *(float4*)(out + base)            = ra;
            *(float4*)(out + base + 197*64)   = rb;   // next head
        } else {
            size_t base = (size_t)row * 768 + n0 + (tx << 2);
            *(float4*)(out + base)      = ra;
            *(float4*)(out + base + 64) = rb;
        }
    }
}

// ---------------------------------------------------------------------------
// relative-position indices (matches the python rel_indices with side=14)
// ---------------------------------------------------------------------------
__device__ __forceinline__ void relidx(int i, int j, int& fv, int& fh) {
    if (i == 0 || j == 0) { fv = 0; fh = 0; return; }
    int qi = i - 1, kj = j - 1;
    int dv = kj / 14 - qi / 14;
    int dh = kj % 14 - qi % 14;
    dv = dv < -14 ? -14 : (dv > 14 ? 14 : dv);
    dh = dh < -14 ? -14 : (dh > 14 ? 14 : dh);
    fv = dv + 15; fh = dh + 15;
}

// ---------------------------------------------------------------------------
// fused attention: one block per (b,h); K,V,tables LDS-resident.
// s_ij = SCALE*(q_i.k_j + q_i.rkv[fv] + q_i.rkh[fh])  (table dots precomputed
// per query, gathered via shfl). Softmax per row. Output:
// o_d = sum_j p_j v_jd + sum_r wv[r]*rvv[r][d] + sum_r wh[r]*rvh[r][d]
// with histogram weights wv/wh accumulated per-lane (bin == lane id).
// ---------------------------------------------------------------------------
__global__ __launch_bounds__(512) void attn_kernel(
    const float* __restrict__ q, const float* __restrict__ k, const float* __restrict__ v,
    const float* __restrict__ rkv, const float* __restrict__ rkh,
    const float* __restrict__ rvv, const float* __restrict__ rvh,
    float* __restrict__ o)
{
    __shared__ float kk_s[197 * KP];
    __shared__ float vv_s[197 * KP];
    __shared__ float tb[4][NT * KP];
    __shared__ float pb[8][256];

    const int bh = blockIdx.x;
    const int b = bh / NH, h = bh % NH;
    const int tid = threadIdx.x;
    const float* kg = k + (size_t)bh * 197 * 64;
    const float* vg = v + (size_t)bh * 197 * 64;

    for (int idx = tid; idx < 197 * 16; idx += 512) {
        int row = idx >> 4, c = (idx & 15) << 2;
        *(float4*)&kk_s[row * KP + c] = *(const float4*)(kg + row * 64 + c);
        *(float4*)&vv_s[row * KP + c] = *(const float4*)(vg + row * 64 + c);
    }
    {
        const float* t0 = rkv; const float* t1 = rkh;
        const float* t2 = rvv; const float* t3 = rvh;
        for (int idx = tid; idx < NT * 16; idx += 512) {
            int row = idx >> 4, c = (idx & 15) << 2;
            *(float4*)&tb[0][row * KP + c] = *(const float4*)(t0 + row * 64 + c);
            *(float4*)&tb[1][row * KP + c] = *(const float4*)(t1 + row * 64 + c);
            *(float4*)&tb[2][row * KP + c] = *(const float4*)(t2 + row * 64 + c);
            *(float4*)&tb[3][row * KP + c] = *(const float4*)(t3 + row * 64 + c);
        }
    }
    __syncthreads();

    const int w = tid >> 6, lane = tid & 63;

    for (int i = w; i < 197; i += 8) {
        // q_i (full 64-dim row per lane; wave-uniform address -> broadcast loads)
        float4 qv[16];
        const float* qg = q + ((size_t)bh * 197 + i) * 64;
        #pragma unroll
        for (int t = 0; t < 16; ++t) qv[t] = *(const float4*)(qg + t * 4);

        // per-query table dots: lanes 0..29 -> rkv rows, lanes 32..61 -> rkh rows
        int rr_ = lane & 31;
        const float* tp = (lane < 32) ? &tb[0][rr_ * KP] : &tb[1][rr_ * KP];
        float tdot = 0.f;
        if (rr_ < NT) {
            #pragma unroll
            for (int t = 0; t < 16; ++t) {
                float4 t4 = *(const float4*)(tp + t * 4);
                tdot += qv[t].x * t4.x + qv[t].y * t4.y + qv[t].z * t4.z + qv[t].w * t4.w;
            }
        }

        // scores
        float s[4];
        float m = -INFINITY;
        #pragma unroll
        for (int jt = 0; jt < 4; ++jt) {
            int j = jt * 64 + lane;
            int jc = (j < 197) ? j : 196;
            int fv, fh; relidx(i, jc, fv, fh);
            const float* kr = &kk_s[jc * KP];
            float accs = 0.f;
            #pragma unroll
            for (int t = 0; t < 16; ++t) {
                float4 k4 = *(const float4*)(kr + t * 4);
                accs += qv[t].x * k4.x + qv[t].y * k4.y + qv[t].z * k4.z + qv[t].w * k4.w;
            }
            float bkv = __shfl(tdot, fv, 64);        // executed by all lanes
            float bkh = __shfl(tdot, fh + 32, 64);
            float sc = (accs + bkv + bkh) * SCALE_;
            s[jt] = (j < 197) ? sc : -INFINITY;
            m = fmaxf(m, s[jt]);
        }
        #pragma unroll
        for (int off = 32; off > 0; off >>= 1) m = fmaxf(m, __shfl_xor(m, off, 64));

        float l = 0.f;
        #pragma unroll
        for (int jt = 0; jt < 4; ++jt) {
            float p = __expf(s[jt] - m);   // -inf -> 0
            l += p;
            pb[w][jt * 64 + lane] = p;
        }
        #pragma unroll
        for (int off = 32; off > 0; off >>= 1) l += __shfl_xor(l, off, 64);
        float rl = 1.f / l;

        // output phase: lane == d
        float acc = 0.f, wv = 0.f, wh = 0.f;
        for (int j = 0; j < 197; ++j) {
            int fv, fh; relidx(i, j, fv, fh);
            float p = pb[w][j];                      // broadcast read (same wave wrote it)
            acc += p * vv_s[j * KP + lane];
            wv += (lane == fv) ? p : 0.f;
            wh += (lane == fh) ? p : 0.f;
        }
        #pragma unroll
        for (int rr = 0; rr < NT; ++rr) {
            float wvr = __shfl(wv, rr, 64);
            float whr = __shfl(wh, rr, 64);
            acc += wvr * tb[2][rr * KP + lane] + whr * tb[3][rr * KP + lane];
        }

        o[((size_t)(b * 197 + i)) * 768 + h * 64 + lane] = acc * rl;
    }
}

// ---------------------------------------------------------------------------
extern "C" void kernel_launch(void* const* d_in, const int* in_sizes, int n_in,
                              void* d_out, int out_size, void* d_ws, size_t ws_size,
                              hipStream_t stream)
{
    const float* x   = (const float*)d_in[0];
    const float* wq  = (const float*)d_in[1];
    const float* bq  = (const float*)d_in[2];
    const float* wk  = (const float*)d_in[3];
    const float* bk  = (const float*)d_in[4];
    const float* wv  = (const float*)d_in[5];
    const float* bv  = (const float*)d_in[6];
    const float* wp  = (const float*)d_in[7];
    const float* bp  = (const float*)d_in[8];
    const float* rkv = (const float*)d_in[9];
    const float* rkh = (const float*)d_in[10];
    const float* rvv = (const float*)d_in[11];
    const float* rvh = (const float*)d_in[12];
    float* out = (float*)d_out;

    const size_t SZ = (size_t)12608 * 768;   // per-tensor elements
    float* qb = (float*)d_ws;
    float* kb = qb + SZ;
    float* vb = kb + SZ;
    float* ob = vb + SZ;

    // QKV projections -> (B,H,N,HD) in workspace
    gemm_kernel<<<dim3(6, 197, 3), 256, 0, stream>>>(
        x, wq, wk, wv, bq, bk, bv, qb, kb, vb, 1);

    // fused attention with iRPE -> (B,N,H*HD) row-major in workspace
    attn_kernel<<<dim3(768), 512, 0, stream>>>(qb, kb, vb, rkv, rkh, rvv, rvh, ob);

    // output projection -> d_out
    gemm_kernel<<<dim3(6, 197, 1), 256, 0, stream>>>(
        ob, wp, wp, wp, bp, bp, bp, out, out, out, 0);
}

// Round 2
// 1629.279 us; speedup vs baseline: 1.9396x; 1.9396x over previous
//
#include <hip/hip_runtime.h>
#include <math.h>

#define NB 64
#define NN 197
#define DD 768
#define NH 12
#define HD_ 64
#define SCALE_ 0.125f

// ---------------------------------------------------------------------------
// GEMM: C(M=12608, 768) = A @ W(768,768) + bias   (unchanged from round 1)
// ---------------------------------------------------------------------------
__global__ __launch_bounds__(256) void gemm_kernel(
    const float* __restrict__ A,
    const float* __restrict__ W0, const float* __restrict__ W1, const float* __restrict__ W2,
    const float* __restrict__ b0, const float* __restrict__ b1, const float* __restrict__ b2,
    float* __restrict__ o0, float* __restrict__ o1, float* __restrict__ o2,
    int scatter)
{
    const float* W = W0; const float* bias = b0; float* out = o0;
    if (blockIdx.z == 1) { W = W1; bias = b1; out = o1; }
    else if (blockIdx.z == 2) { W = W2; bias = b2; out = o2; }

    __shared__ float As[16][64];
    __shared__ float Ws[16][128];

    const int tid = threadIdx.x;
    const int m0 = blockIdx.y * 64;
    const int n0 = blockIdx.x * 128;

    const int alr = tid >> 2;
    const int alk = (tid & 3) << 2;
    const int wr0 = tid >> 5;
    const int wc0 = (tid & 31) << 2;

    const int tx = tid & 15;
    const int ty = tid >> 4;

    float acc[4][8];
    #pragma unroll
    for (int r = 0; r < 4; ++r)
        #pragma unroll
        for (int u = 0; u < 8; ++u) acc[r][u] = 0.f;

    for (int kt = 0; kt < 768; kt += 16) {
        float4 av  = *(const float4*)(A + (size_t)(m0 + alr)*768 + kt + alk);
        float4 w4a = *(const float4*)(W + (size_t)(kt + wr0)*768 + n0 + wc0);
        float4 w4b = *(const float4*)(W + (size_t)(kt + wr0 + 8)*768 + n0 + wc0);
        __syncthreads();
        As[alk+0][alr] = av.x;
        As[alk+1][alr] = av.y;
        As[alk+2][alr] = av.z;
        As[alk+3][alr] = av.w;
        *(float4*)&Ws[wr0][wc0]     = w4a;
        *(float4*)&Ws[wr0+8][wc0]   = w4b;
        __syncthreads();
        #pragma unroll
        for (int kk = 0; kk < 16; ++kk) {
            float4 a4  = *(const float4*)&As[kk][ty << 2];
            float4 b4a = *(const float4*)&Ws[kk][tx << 2];
            float4 b4b = *(const float4*)&Ws[kk][(tx << 2) + 64];
            float ar[4] = {a4.x, a4.y, a4.z, a4.w};
            float br[8] = {b4a.x, b4a.y, b4a.z, b4a.w, b4b.x, b4b.y, b4b.z, b4b.w};
            #pragma unroll
            for (int r = 0; r < 4; ++r)
                #pragma unroll
                for (int u = 0; u < 8; ++u)
                    acc[r][u] += ar[r] * br[u];
        }
    }

    float4 biasA = *(const float4*)(bias + n0 + (tx << 2));
    float4 biasB = *(const float4*)(bias + n0 + 64 + (tx << 2));
    const int h0 = blockIdx.x << 1;

    #pragma unroll
    for (int r = 0; r < 4; ++r) {
        int row = m0 + (ty << 2) + r;
        float4 ra, rb;
        ra.x = acc[r][0] + biasA.x; ra.y = acc[r][1] + biasA.y;
        ra.z = acc[r][2] + biasA.z; ra.w = acc[r][3] + biasA.w;
        rb.x = acc[r][4] + biasB.x; rb.y = acc[r][5] + biasB.y;
        rb.z = acc[r][6] + biasB.z; rb.w = acc[r][7] + biasB.w;
        if (scatter) {
            int bb = row / 197;
            int nn = row - bb * 197;
            size_t base = ((size_t)(bb * NH + h0) * 197 + nn) * 64 + (tx << 2);
            *(float4*)(out + base)            = ra;
            *(float4*)(out + base + 197*64)   = rb;
        } else {
            size_t base = (size_t)row * 768 + n0 + (tx << 2);
            *(float4*)(out + base)      = ra;
            *(float4*)(out + base + 64) = rb;
        }
    }
}

// ---------------------------------------------------------------------------
// Fused attention v2: GEMM-structured per (b,h,qtile-of-64).
// Phase 1: S^T[j][ii] = q.k (outer-product GEMM) + rel-k bias from Tvh.
// Softmax pass: per-query max/exp/sum + LDS-atomic histograms (Wv,Wh) stored
//   as extra rows of St.
// Phase 2: O = [P | Wv | Wh] . [V ; rvv ; rvh]  (single K=260 GEMM), scaled
//   by 1/l at the epilogue.
// LDS: U (Kt[64][200] + Qt[64][68], overlaid later by St[260][68]) 70,720 B
//      Vx[264][64] 67,584 B   Tvh[64][64] 16,384 B   rl[64] 256 B
//      total 154,944 B -> 1 block/CU, 8 waves.
// ---------------------------------------------------------------------------
__global__ __launch_bounds__(512) void attn_kernel(
    const float* __restrict__ q, const float* __restrict__ k, const float* __restrict__ v,
    const float* __restrict__ rkv, const float* __restrict__ rkh,
    const float* __restrict__ rvv, const float* __restrict__ rvh,
    float* __restrict__ o)
{
    __shared__ float U[17680];        // Kt[0,12800) Qt[12800,17152) ; St=U[260][68]
    __shared__ float Vx[264 * 64];    // rows 0..196 V; 197..199 zero; 200..263 Tt then rvv/rvh
    __shared__ float Tvh[64 * 64];    // [ii][col]: col 0..29 = q.rkv[r], 32..61 = q.rkh[r]
    __shared__ float rl[64];

    float* Kt = U;            // [64][200]
    float* Qt = U + 12800;    // [64][68]
    float* St = U;            // [260][68]

    const int bh = blockIdx.y;
    const int qt = blockIdx.x;
    const int b = bh / NH, h = bh % NH;
    const int I0 = qt * 64;
    const int tid = threadIdx.x;

    const float* qg = q + (size_t)bh * 197 * 64;
    const float* kg = k + (size_t)bh * 197 * 64;
    const float* vg = v + (size_t)bh * 197 * 64;

    // ---- stage K transposed: Kt[d][j] = K[j][d]
    for (int idx = tid; idx < 197 * 16; idx += 512) {
        int j = idx % 197, c4 = idx / 197;
        float4 g = *(const float4*)(kg + j * 64 + c4 * 4);
        float* lp = Kt + (c4 * 4) * 200 + j;
        lp[0] = g.x; lp[200] = g.y; lp[400] = g.z; lp[600] = g.w;
    }
    // ---- stage Q transposed (zero-padded): Qt[d][ii]
    for (int idx = tid; idx < 64 * 16; idx += 512) {
        int ii = idx & 63, c4 = idx >> 6;
        int i = I0 + ii;
        float4 g = make_float4(0.f, 0.f, 0.f, 0.f);
        if (i < 197) g = *(const float4*)(qg + i * 64 + c4 * 4);
        float* lp = Qt + (c4 * 4) * 68 + ii;
        lp[0] = g.x; lp[68] = g.y; lp[136] = g.z; lp[204] = g.w;
    }
    // ---- stage V direct: Vx[j][d]
    for (int idx = tid; idx < 197 * 16; idx += 512) {
        int j = idx >> 4, c4 = idx & 15;
        *(float4*)(Vx + j * 64 + c4 * 4) = *(const float4*)(vg + j * 64 + c4 * 4);
    }
    if (tid < 192) Vx[197 * 64 + tid] = 0.f;   // zero pad rows 197..199
    // ---- stage rel-k tables transposed: Tt[d][col] at Vx rows 200+d
    for (int idx = tid; idx < 64 * 64; idx += 512) {
        int col = idx & 63, d = idx >> 6;
        int r = col & 31, t = col >> 5;
        float val = 0.f;
        if (r < 30) val = (t ? rkh : rkv)[r * 64 + d];
        Vx[(200 + d) * 64 + col] = val;
    }
    __syncthreads();

    const int tx = tid & 31, ty = tid >> 5;   // 32 x 16

    // ---- Tvh GEMM: Tvh[ii][col] = sum_d Qt[d][ii] * Tt[d][col]
    {
        float a00=0,a01=0,a10=0,a11=0,a20=0,a21=0,a30=0,a31=0;
        #pragma unroll 4
        for (int kk = 0; kk < 64; ++kk) {
            float4 q4 = *(const float4*)(Qt + kk * 68 + ty * 4);
            float2 t2 = *(const float2*)(Vx + (200 + kk) * 64 + tx * 2);
            a00 += q4.x * t2.x; a01 += q4.x * t2.y;
            a10 += q4.y * t2.x; a11 += q4.y * t2.y;
            a20 += q4.z * t2.x; a21 += q4.z * t2.y;
            a30 += q4.w * t2.x; a31 += q4.w * t2.y;
        }
        *(float2*)(Tvh + (ty * 4 + 0) * 64 + tx * 2) = make_float2(a00, a01);
        *(float2*)(Tvh + (ty * 4 + 1) * 64 + tx * 2) = make_float2(a10, a11);
        *(float2*)(Tvh + (ty * 4 + 2) * 64 + tx * 2) = make_float2(a20, a21);
        *(float2*)(Tvh + (ty * 4 + 3) * 64 + tx * 2) = make_float2(a30, a31);
    }
    __syncthreads();   // Tt reads done; Tvh visible after next barrier anyway

    // ---- stage rvv/rvh into Vx rows 200..259 (overwrites Tt)
    for (int idx = tid; idx < 60 * 16; idx += 512) {
        int rr = idx >> 4, c4 = idx & 15;
        const float* src = (rr < 30) ? (rvv + rr * 64) : (rvh + (rr - 30) * 64);
        *(float4*)(Vx + (200 + rr) * 64 + c4 * 4) = *(const float4*)(src + c4 * 4);
    }

    // ---- phase-1 GEMM: S[ii][j] for ii = 4ty+r, j = 128u + 4tx + e
    float acc[4][8];
    #pragma unroll
    for (int r = 0; r < 4; ++r)
        #pragma unroll
        for (int u = 0; u < 8; ++u) acc[r][u] = 0.f;

    #pragma unroll 4
    for (int kk = 0; kk < 64; ++kk) {
        float4 q4 = *(const float4*)(Qt + kk * 68 + ty * 4);
        float4 ka = *(const float4*)(Kt + kk * 200 + tx * 4);
        float4 kb = *(const float4*)(Kt + kk * 200 + 128 + tx * 4);
        float qr[4] = {q4.x, q4.y, q4.z, q4.w};
        float kw[8] = {ka.x, ka.y, ka.z, ka.w, kb.x, kb.y, kb.z, kb.w};
        #pragma unroll
        for (int r = 0; r < 4; ++r)
            #pragma unroll
            for (int u = 0; u < 8; ++u)
                acc[r][u] += qr[r] * kw[u];
    }
    __syncthreads();   // Kt/Qt dead -> U becomes St

    // ---- zero histogram rows (St rows 200..259)
    for (int idx = tid; idx < 60 * 64; idx += 512)
        St[(200 + (idx >> 6)) * 68 + (idx & 63)] = 0.f;

    // ---- epilogue: add rel-k bias, scale, write St[j][ii] (zeros for j>=197)
    {
        int iv4[4], ih4[4];
        #pragma unroll
        for (int r = 0; r < 4; ++r) {
            int i = I0 + ty * 4 + r;
            int qi = i - 1;
            int dv = qi / 14;
            iv4[r] = dv; ih4[r] = qi - dv * 14;
        }
        #pragma unroll
        for (int u = 0; u < 2; ++u) {
            int jbase = u * 128 + tx * 4;
            if (jbase >= 200) continue;
            #pragma unroll
            for (int e = 0; e < 4; ++e) {
                int j = jbase + e;
                int kj = j - 1;
                int jv = kj / 14;
                int jh = kj - jv * 14;
                float out4[4];
                #pragma unroll
                for (int r = 0; r < 4; ++r) {
                    float s = 0.f;
                    if (j < 197) {
                        int i = I0 + ty * 4 + r;
                        int fv = 0, fh = 0;
                        if (i > 0 && j > 0) {
                            int dv = jv - iv4[r]; dv = min(14, max(-14, dv));
                            int dh = jh - ih4[r]; dh = min(14, max(-14, dh));
                            fv = dv + 15; fh = dh + 15;
                        }
                        s = (acc[r][u * 4 + e]
                             + Tvh[(ty * 4 + r) * 64 + fv]
                             + Tvh[(ty * 4 + r) * 64 + 32 + fh]) * SCALE_;
                    }
                    out4[r] = s;
                }
                *(float4*)(St + j * 68 + ty * 4) =
                    make_float4(out4[0], out4[1], out4[2], out4[3]);
            }
        }
    }
    __syncthreads();

    // ---- softmax + histograms; wave w owns queries ii = w, w+8, ...
    {
        const int w = tid >> 6, lane = tid & 63;
        for (int ii = w; ii < 64; ii += 8) {
            float sv[4];
            #pragma unroll
            for (int u = 0; u < 4; ++u) {
                int j = u * 64 + lane;
                sv[u] = (j < 197) ? St[j * 68 + ii] : -INFINITY;
            }
            float m = fmaxf(fmaxf(sv[0], sv[1]), fmaxf(sv[2], sv[3]));
            #pragma unroll
            for (int off = 32; off > 0; off >>= 1) m = fmaxf(m, __shfl_xor(m, off, 64));
            float p[4], l = 0.f;
            #pragma unroll
            for (int u = 0; u < 4; ++u) {
                int j = u * 64 + lane;
                p[u] = (j < 197) ? __expf(sv[u] - m) : 0.f;
                l += p[u];
            }
            #pragma unroll
            for (int off = 32; off > 0; off >>= 1) l += __shfl_xor(l, off, 64);
            if (lane == 0) rl[ii] = 1.f / l;
            #pragma unroll
            for (int u = 0; u < 4; ++u) {
                int j = u * 64 + lane;
                if (j < 200) St[j * 68 + ii] = p[u];
            }
            // histograms (unnormalized; normalization folded into epilogue)
            int i = I0 + ii;
            int qi = i - 1;
            int iv = qi / 14, ih = qi - (qi / 14) * 14;
            #pragma unroll
            for (int u = 0; u < 4; ++u) {
                int j = u * 64 + lane;
                if (j < 197) {
                    int fv = 0, fh = 0;
                    if (i > 0 && j > 0) {
                        int kj = j - 1;
                        int jv = kj / 14, jh = kj - (kj / 14) * 14;
                        int dv = jv - iv; dv = min(14, max(-14, dv));
                        int dh = jh - ih; dh = min(14, max(-14, dh));
                        fv = dv + 15; fh = dh + 15;
                    }
                    atomicAdd(&St[(200 + fv) * 68 + ii], p[u]);
                    atomicAdd(&St[(230 + fh) * 68 + ii], p[u]);
                }
            }
        }
    }
    __syncthreads();

    // ---- phase-2 GEMM: O[ii][d] = sum_{kk<260} St[kk][ii] * Vx[kk][d]
    {
        float o00=0,o01=0,o10=0,o11=0,o20=0,o21=0,o30=0,o31=0;
        #pragma unroll 4
        for (int kk = 0; kk < 260; ++kk) {
            float4 a4 = *(const float4*)(St + kk * 68 + ty * 4);
            float2 v2 = *(const float2*)(Vx + kk * 64 + tx * 2);
            o00 += a4.x * v2.x; o01 += a4.x * v2.y;
            o10 += a4.y * v2.x; o11 += a4.y * v2.y;
            o20 += a4.z * v2.x; o21 += a4.z * v2.y;
            o30 += a4.w * v2.x; o31 += a4.w * v2.y;
        }
        float res[4][2] = {{o00,o01},{o10,o11},{o20,o21},{o30,o31}};
        #pragma unroll
        for (int r = 0; r < 4; ++r) {
            int ii = ty * 4 + r;
            int i = I0 + ii;
            if (i < 197) {
                float s = rl[ii];
                *(float2*)(o + ((size_t)(b * 197 + i)) * 768 + h * 64 + tx * 2)
                    = make_float2(res[r][0] * s, res[r][1] * s);
            }
        }
    }
}

// ---------------------------------------------------------------------------
extern "C" void kernel_launch(void* const* d_in, const int* in_sizes, int n_in,
                              void* d_out, int out_size, void* d_ws, size_t ws_size,
                              hipStream_t stream)
{
    const float* x   = (const float*)d_in[0];
    const float* wq  = (const float*)d_in[1];
    const float* bq  = (const float*)d_in[2];
    const float* wk  = (const float*)d_in[3];
    const float* bk  = (const float*)d_in[4];
    const float* wv  = (const float*)d_in[5];
    const float* bv  = (const float*)d_in[6];
    const float* wp  = (const float*)d_in[7];
    const float* bp  = (const float*)d_in[8];
    const float* rkv = (const float*)d_in[9];
    const float* rkh = (const float*)d_in[10];
    const float* rvv = (const float*)d_in[11];
    const float* rvh = (const float*)d_in[12];
    float* out = (float*)d_out;

    const size_t SZ = (size_t)12608 * 768;
    float* qb = (float*)d_ws;
    float* kb = qb + SZ;
    float* vb = kb + SZ;
    float* ob = vb + SZ;

    gemm_kernel<<<dim3(6, 197, 3), 256, 0, stream>>>(
        x, wq, wk, wv, bq, bk, bv, qb, kb, vb, 1);

    attn_kernel<<<dim3(4, 768), 512, 0, stream>>>(
        qb, kb, vb, rkv, rkh, rvv, rvh, ob);

    gemm_kernel<<<dim3(6, 197, 1), 256, 0, stream>>>(
        ob, wp, wp, wp, bp, bp, bp, out, out, out, 0);
}

// Round 3
// 608.225 us; speedup vs baseline: 5.1958x; 2.6787x over previous
//
#include <hip/hip_runtime.h>
#include <math.h>

#define SCALE_ 0.125f

typedef unsigned short u16;
typedef __attribute__((ext_vector_type(8))) short short8;
typedef __attribute__((ext_vector_type(4))) float f32x4;
#define MFMA __builtin_amdgcn_mfma_f32_16x16x32_bf16

__device__ __forceinline__ u16 f2bf(float f) {
    unsigned int u = __float_as_uint(f);
    unsigned int r = (u + 0x7fffu + ((u >> 16) & 1u)) >> 16;
    return (u16)r;
}
__device__ __forceinline__ float bf2f(u16 h) {
    return __uint_as_float(((unsigned int)h) << 16);
}

// ---------------------------------------------------------------------------
// prep: split x into hi/lo bf16
// ---------------------------------------------------------------------------
__global__ void prep_split_x(const float* __restrict__ x, u16* __restrict__ xh,
                             u16* __restrict__ xl) {
    size_t idx = ((size_t)blockIdx.x * 256 + threadIdx.x) * 8;
    float4 a = *(const float4*)(x + idx), b = *(const float4*)(x + idx + 4);
    float f[8] = {a.x, a.y, a.z, a.w, b.x, b.y, b.z, b.w};
    u16 hs[8], ls[8];
    #pragma unroll
    for (int e = 0; e < 8; ++e) {
        hs[e] = f2bf(f[e]);
        ls[e] = f2bf(f[e] - bf2f(hs[e]));
    }
    *(uint4*)(xh + idx) = *(uint4*)hs;
    *(uint4*)(xl + idx) = *(uint4*)ls;
}

// ---------------------------------------------------------------------------
// prep: transpose + split weights: Wt[n][k] = W[k][n], hi/lo bf16
// ---------------------------------------------------------------------------
__global__ void prep_w(const float* __restrict__ w0, const float* __restrict__ w1,
                       const float* __restrict__ w2, const float* __restrict__ w3,
                       u16* o0h, u16* o0l, u16* o1h, u16* o1l,
                       u16* o2h, u16* o2l, u16* o3h, u16* o3l) {
    const float* W; u16* oh; u16* ol;
    if (blockIdx.z == 0)      { W = w0; oh = o0h; ol = o0l; }
    else if (blockIdx.z == 1) { W = w1; oh = o1h; ol = o1l; }
    else if (blockIdx.z == 2) { W = w2; oh = o2h; ol = o2l; }
    else                      { W = w3; oh = o3h; ol = o3l; }

    __shared__ float t[64 * 68];
    int k0 = blockIdx.y * 64, n0 = blockIdx.x * 64;
    int tid = threadIdx.x;
    #pragma unroll
    for (int rr = 0; rr < 4; ++rr) {
        int r = (tid >> 4) + rr * 16;
        int c = (tid & 15) * 4;
        *(float4*)&t[r * 68 + c] = *(const float4*)(W + (size_t)(k0 + r) * 768 + n0 + c);
    }
    __syncthreads();
    int n = tid >> 2, kc = (tid & 3) * 16;
    u16 hs[16], ls[16];
    #pragma unroll
    for (int e = 0; e < 16; ++e) {
        float f = t[(kc + e) * 68 + n];
        hs[e] = f2bf(f);
        ls[e] = f2bf(f - bf2f(hs[e]));
    }
    size_t o = (size_t)(n0 + n) * 768 + k0 + kc;
    *(uint4*)(oh + o) = *(uint4*)hs;  *(uint4*)(oh + o + 8) = *(uint4*)(hs + 8);
    *(uint4*)(ol + o) = *(uint4*)ls;  *(uint4*)(ol + o + 8) = *(uint4*)(ls + 8);
}

// ---------------------------------------------------------------------------
// prep: tables. Tk[r][d] (r: 0..29 rkv, 32..61 rkh, zeros elsewhere) hi/lo;
// Rt[d][r] = rel_v tables transposed, hi only.
// ---------------------------------------------------------------------------
__global__ void prep_tabs(const float* __restrict__ rkv, const float* __restrict__ rkh,
                          const float* __restrict__ rvv, const float* __restrict__ rvh,
                          u16* tkh, u16* tkl, u16* rth) {
    for (int idx = threadIdx.x; idx < 4096; idx += 256) {
        int r = idx >> 6, d = idx & 63;
        float tv = 0.f;
        if (r < 30) tv = rkv[r * 64 + d];
        else if (r >= 32 && r < 62) tv = rkh[(r - 32) * 64 + d];
        u16 hs = f2bf(tv);
        tkh[idx] = hs;
        tkl[idx] = f2bf(tv - bf2f(hs));
        int dd = idx >> 6, rr = idx & 63;
        float vv = 0.f;
        if (rr < 30) vv = rvv[rr * 64 + dd];
        else if (rr >= 32 && rr < 62) vv = rvh[(rr - 32) * 64 + dd];
        rth[idx] = f2bf(vv);
    }
}

// ---------------------------------------------------------------------------
// Split-bf16 MFMA GEMM: C(12608,768) = A(12608,768) @ B(768,768) + bias
// A given as hi/lo bf16 row-major; B given as Bt[n][k] hi/lo bf16.
// 3 passes: hi*hi + hi*lo + lo*hi, fp32 accum.
// mode 0: scatter-split epilogue to (B,H,N,64) hi/lo bf16 (lo skipped if null)
// mode 1: plain fp32 output
// ---------------------------------------------------------------------------
__global__ __launch_bounds__(256, 3) void gemm_bf16(
    const u16* __restrict__ Ah, const u16* __restrict__ Al,
    const u16* __restrict__ Bt0h, const u16* __restrict__ Bt0l,
    const u16* __restrict__ Bt1h, const u16* __restrict__ Bt1l,
    const u16* __restrict__ Bt2h, const u16* __restrict__ Bt2l,
    const float* __restrict__ bias0, const float* __restrict__ bias1,
    const float* __restrict__ bias2,
    u16* o0h, u16* o0l, u16* o1h, u16* o1l, u16* o2h, u16* o2l,
    float* outf, int mode)
{
    const u16* Bh = Bt0h; const u16* Bl = Bt0l; const float* bias = bias0;
    u16* out_h = o0h; u16* out_l = o0l;
    if (blockIdx.z == 1) { Bh = Bt1h; Bl = Bt1l; bias = bias1; out_h = o1h; out_l = o1l; }
    else if (blockIdx.z == 2) { Bh = Bt2h; Bl = Bt2l; bias = bias2; out_h = o2h; out_l = o2l; }

    __shared__ u16 Ahs[128 * 40];
    __shared__ u16 Als[128 * 40];
    __shared__ u16 Bhs[128 * 40];
    __shared__ u16 Bls[128 * 40];

    const int tid = threadIdx.x;
    const int m0 = blockIdx.y * 128, n0 = blockIdx.x * 128;
    const int w = tid >> 6, lane = tid & 63, quad = lane >> 4, l16 = lane & 15;
    const int wm = (w >> 1) * 64, wn = (w & 1) * 64;
    const int srow = tid >> 1, shalf = tid & 1;

    f32x4 acc[4][4];
    #pragma unroll
    for (int a = 0; a < 4; ++a)
        #pragma unroll
        for (int b = 0; b < 4; ++b) acc[a][b] = (f32x4){0, 0, 0, 0};

    for (int kt = 0; kt < 768; kt += 32) {
        int arow = m0 + srow;
        uint4 a0, a1, l0, l1;
        if (arow < 12608) {
            size_t aoff = (size_t)arow * 768 + kt + shalf * 16;
            a0 = *(const uint4*)(Ah + aoff);  a1 = *(const uint4*)(Ah + aoff + 8);
            l0 = *(const uint4*)(Al + aoff);  l1 = *(const uint4*)(Al + aoff + 8);
        } else {
            a0 = a1 = l0 = l1 = make_uint4(0, 0, 0, 0);
        }
        size_t boff = (size_t)(n0 + srow) * 768 + kt + shalf * 16;
        uint4 b0 = *(const uint4*)(Bh + boff), b1 = *(const uint4*)(Bh + boff + 8);
        uint4 c0 = *(const uint4*)(Bl + boff), c1 = *(const uint4*)(Bl + boff + 8);
        __syncthreads();
        *(uint4*)&Ahs[srow * 40 + shalf * 16]     = a0;
        *(uint4*)&Ahs[srow * 40 + shalf * 16 + 8] = a1;
        *(uint4*)&Als[srow * 40 + shalf * 16]     = l0;
        *(uint4*)&Als[srow * 40 + shalf * 16 + 8] = l1;
        *(uint4*)&Bhs[srow * 40 + shalf * 16]     = b0;
        *(uint4*)&Bhs[srow * 40 + shalf * 16 + 8] = b1;
        *(uint4*)&Bls[srow * 40 + shalf * 16]     = c0;
        *(uint4*)&Bls[srow * 40 + shalf * 16 + 8] = c1;
        __syncthreads();

        short8 ah[4], al[4];
        #pragma unroll
        for (int mi = 0; mi < 4; ++mi) {
            ah[mi] = *(const short8*)&Ahs[(wm + mi * 16 + l16) * 40 + quad * 8];
            al[mi] = *(const short8*)&Als[(wm + mi * 16 + l16) * 40 + quad * 8];
        }
        #pragma unroll
        for (int ni = 0; ni < 4; ++ni) {
            short8 bhf = *(const short8*)&Bhs[(wn + ni * 16 + l16) * 40 + quad * 8];
            short8 blf = *(const short8*)&Bls[(wn + ni * 16 + l16) * 40 + quad * 8];
            #pragma unroll
            for (int mi = 0; mi < 4; ++mi) {
                acc[mi][ni] = MFMA(ah[mi], bhf, acc[mi][ni], 0, 0, 0);
                acc[mi][ni] = MFMA(ah[mi], blf, acc[mi][ni], 0, 0, 0);
                acc[mi][ni] = MFMA(al[mi], bhf, acc[mi][ni], 0, 0, 0);
            }
        }
    }

    #pragma unroll
    for (int mi = 0; mi < 4; ++mi) {
        #pragma unroll
        for (int r = 0; r < 4; ++r) {
            int gr = m0 + wm + mi * 16 + quad * 4 + r;
            if (gr >= 12608) continue;
            int bb = 0, ii = 0;
            if (mode == 0) { bb = gr / 197; ii = gr - bb * 197; }
            #pragma unroll
            for (int ni = 0; ni < 4; ++ni) {
                int gc = n0 + wn + ni * 16 + l16;
                float val = acc[mi][ni][r] + bias[gc];
                if (mode == 0) {
                    int h = gc >> 6, d = gc & 63;
                    size_t addr = ((size_t)(bb * 12 + h) * 197 + ii) * 64 + d;
                    u16 hs = f2bf(val);
                    out_h[addr] = hs;
                    if (out_l) out_l[addr] = f2bf(val - bf2f(hs));
                } else {
                    outf[(size_t)gr * 768 + gc] = val;
                }
            }
        }
    }
}

// ---------------------------------------------------------------------------
// Fused attention, split-bf16 MFMA. One block per (qtile64, b*h). 512 thr.
// Phase 0: Tvh[m][col] = q_m . Tk[col]          (3-pass MFMA)
// Phase 1: S[m][j] = q_m . k_j                   (3-pass MFMA) + rel-k bias
// Softmax (fp32) + shfl-based rel-v histograms into S cols 208..271
// Phase 2: O[m][d] = P_aug . [V ; rel_v^T]       (2-pass MFMA, K=288)
// ---------------------------------------------------------------------------
__global__ __launch_bounds__(512) void attn_mfma(
    const u16* __restrict__ qh, const u16* __restrict__ ql,
    const u16* __restrict__ kh, const u16* __restrict__ kl,
    const u16* __restrict__ vh,
    const u16* __restrict__ tkh, const u16* __restrict__ tkl,
    const u16* __restrict__ rth,
    u16* __restrict__ oh, u16* __restrict__ ol)
{
    __shared__ __align__(16) char smem[152064];
    float* St    = (float*)smem;               // [64][292] fp32
    u16*   Khs   = (u16*)(smem + 74752);       // [208][72]
    u16*   Kls   = Khs + 208 * 72;
    float* Tvh   = (float*)(smem + 134656);    // [64][68]
    u16*   Vts   = (u16*)(smem + 74752);       // [64][296] (phase 2, overlays K)
    u16*   Tkh_s = (u16*)smem;                 // staging (overlaid by St later)
    u16*   Tkl_s = Tkh_s + 64 * 72;
    u16*   Qh_s  = (u16*)(smem + 18432);
    u16*   Ql_s  = Qh_s + 64 * 72;

    const int qt = blockIdx.x, bh = blockIdx.y;
    const int I0 = qt * 64;
    const int tid = threadIdx.x;
    const int w = tid >> 6, lane = tid & 63, quad = lane >> 4, l16 = lane & 15;
    const size_t base = (size_t)bh * 197 * 64;

    // ---- stage Q, Tk, K
    {
        int ii = tid >> 3, part = tid & 7;
        int i = I0 + ii;
        uint4 z = make_uint4(0, 0, 0, 0);
        uint4 gqh = (i < 197) ? *(const uint4*)(qh + base + (size_t)i * 64 + part * 8) : z;
        uint4 gql = (i < 197) ? *(const uint4*)(ql + base + (size_t)i * 64 + part * 8) : z;
        *(uint4*)&Qh_s[ii * 72 + part * 8] = gqh;
        *(uint4*)&Ql_s[ii * 72 + part * 8] = gql;
        *(uint4*)&Tkh_s[ii * 72 + part * 8] = *(const uint4*)(tkh + ii * 64 + part * 8);
        *(uint4*)&Tkl_s[ii * 72 + part * 8] = *(const uint4*)(tkl + ii * 64 + part * 8);
    }
    for (int idx = tid; idx < 208 * 8; idx += 512) {
        int j = idx >> 3, part = idx & 7;
        uint4 z = make_uint4(0, 0, 0, 0);
        uint4 a = (j < 197) ? *(const uint4*)(kh + base + (size_t)j * 64 + part * 8) : z;
        uint4 b = (j < 197) ? *(const uint4*)(kl + base + (size_t)j * 64 + part * 8) : z;
        *(uint4*)&Khs[j * 72 + part * 8] = a;
        *(uint4*)&Kls[j * 72 + part * 8] = b;
    }
    __syncthreads();

    const int mf = w >> 1, nh = w & 1;
    const int mr0 = mf * 16;

    // ---- per-wave Q A-frags
    short8 qah[2], qal[2];
    #pragma unroll
    for (int kb = 0; kb < 2; ++kb) {
        qah[kb] = *(const short8*)&Qh_s[(mr0 + l16) * 72 + kb * 32 + quad * 8];
        qal[kb] = *(const short8*)&Ql_s[(mr0 + l16) * 72 + kb * 32 + quad * 8];
    }

    // ---- phase 0: Tvh GEMM
    #pragma unroll
    for (int s = 0; s < 2; ++s) {
        int nf = nh * 2 + s;
        f32x4 c = (f32x4){0, 0, 0, 0};
        #pragma unroll
        for (int kb = 0; kb < 2; ++kb) {
            short8 bhf = *(const short8*)&Tkh_s[(nf * 16 + l16) * 72 + kb * 32 + quad * 8];
            short8 blf = *(const short8*)&Tkl_s[(nf * 16 + l16) * 72 + kb * 32 + quad * 8];
            c = MFMA(qah[kb], bhf, c, 0, 0, 0);
            c = MFMA(qah[kb], blf, c, 0, 0, 0);
            c = MFMA(qal[kb], bhf, c, 0, 0, 0);
        }
        #pragma unroll
        for (int r = 0; r < 4; ++r)
            Tvh[(mr0 + quad * 4 + r) * 68 + nf * 16 + l16] = c[r];
    }

    // ---- phase 1: scores (7 n-frags per wave; nh=1's last frag is OOR junk,
    //      masked in the epilogue by j<197)
    f32x4 sacc[7];
    #pragma unroll
    for (int s = 0; s < 7; ++s) sacc[s] = (f32x4){0, 0, 0, 0};
    #pragma unroll
    for (int s = 0; s < 7; ++s) {
        int nf = nh * 7 + s;
        f32x4 c = sacc[s];
        #pragma unroll
        for (int kb = 0; kb < 2; ++kb) {
            short8 bhf = *(const short8*)&Khs[(nf * 16 + l16) * 72 + kb * 32 + quad * 8];
            short8 blf = *(const short8*)&Kls[(nf * 16 + l16) * 72 + kb * 32 + quad * 8];
            c = MFMA(qah[kb], bhf, c, 0, 0, 0);
            c = MFMA(qah[kb], blf, c, 0, 0, 0);
            c = MFMA(qal[kb], bhf, c, 0, 0, 0);
        }
        sacc[s] = c;
    }
    __syncthreads();   // Q/Tk/K reads done; Tvh visible

    // ---- epilogue: rel-k bias + scale, write S
    #pragma unroll
    for (int s = 0; s < 7; ++s) {
        int nf = nh * 7 + s;
        int j = nf * 16 + l16;
        if (j < 197) {
            int kj = j - 1;
            int jv = kj / 14, jh = kj - jv * 14;
            #pragma unroll
            for (int r = 0; r < 4; ++r) {
                int m = mr0 + quad * 4 + r;
                int i = I0 + m;
                int fv = 0, fh = 0;
                if (i > 0 && j > 0) {
                    int qi = i - 1;
                    int iv = qi / 14, ih = qi - iv * 14;
                    int dv = jv - iv; dv = min(14, max(-14, dv));
                    int dh = jh - ih; dh = min(14, max(-14, dh));
                    fv = dv + 15; fh = dh + 15;
                }
                St[m * 292 + j] =
                    (sacc[s][r] + Tvh[m * 68 + fv] + Tvh[m * 68 + 32 + fh]) * SCALE_;
            }
        }
    }
    __syncthreads();

    // ---- stage Vt (K region dead) + rel-v tables + zero pads
    {
        int keyl = tid & 63, dgrp = tid >> 6;
        #pragma unroll
        for (int kb = 0; kb < 4; ++kb) {
            int key = kb * 64 + keyl;
            uint4 g = make_uint4(0, 0, 0, 0);
            if (key < 197) g = *(const uint4*)(vh + base + (size_t)key * 64 + dgrp * 8);
            if (key < 208) {
                u16 tmp[8]; *(uint4*)tmp = g;
                #pragma unroll
                for (int e = 0; e < 8; ++e) Vts[(dgrp * 8 + e) * 296 + key] = tmp[e];
            }
        }
        int d = tid >> 3, rblk = tid & 7;
        uint4 g = *(const uint4*)(rth + d * 64 + rblk * 8);
        u16 tmp[8]; *(uint4*)tmp = g;
        #pragma unroll
        for (int e = 0; e < 8; ++e) {
            int r = rblk * 8 + e;
            int col = (r < 32) ? 208 + r : 240 + (r - 32);
            Vts[d * 296 + col] = tmp[e];
        }
        for (int idx = tid; idx < 64 * 16; idx += 512)
            Vts[(idx >> 4) * 296 + 272 + (idx & 15)] = 0;
    }

    // ---- softmax + shfl-based histograms (wave w owns rows 8w..8w+7)
    for (int qq = 0; qq < 8; ++qq) {
        int m = w * 8 + qq;
        int i = I0 + m;
        if (i >= 197) break;
        float sv[4], p[4];
        #pragma unroll
        for (int u = 0; u < 4; ++u) {
            int j = u * 64 + lane;
            sv[u] = (j < 197) ? St[m * 292 + j] : -1e30f;
        }
        float mx = fmaxf(fmaxf(sv[0], sv[1]), fmaxf(sv[2], sv[3]));
        #pragma unroll
        for (int off = 32; off; off >>= 1) mx = fmaxf(mx, __shfl_xor(mx, off, 64));
        float l = 0.f;
        #pragma unroll
        for (int u = 0; u < 4; ++u) {
            int j = u * 64 + lane;
            p[u] = (j < 197) ? __expf(sv[u] - mx) : 0.f;
            l += p[u];
        }
        #pragma unroll
        for (int off = 32; off; off >>= 1) l += __shfl_xor(l, off, 64);
        float rl = 1.f / l;
        #pragma unroll
        for (int u = 0; u < 4; ++u) p[u] *= rl;
        #pragma unroll
        for (int u = 0; u < 4; ++u) {
            int j = u * 64 + lane;
            St[m * 292 + j] = (j < 197) ? p[u] : 0.f;
        }
        if (lane < 32) St[m * 292 + 256 + lane] = 0.f;

        float bs = 0.f;
        if (lane < 14) {
            #pragma unroll
            for (int c = 0; c < 14; ++c) bs += St[m * 292 + 1 + lane * 14 + c];
        } else if (lane >= 16 && lane < 30) {
            int c = lane - 16;
            #pragma unroll
            for (int b = 0; b < 14; ++b) bs += St[m * 292 + 1 + b * 14 + c];
        }
        float pcls = __shfl(p[0], 0, 64);
        float val;
        if (i == 0) {
            val = (lane == 0 || lane == 32) ? 1.f : 0.f;
        } else {
            int qi = i - 1;
            int iv = qi / 14, ih = qi - iv * 14;
            int r = lane & 31;
            int bidx = (lane < 32) ? (r + iv - 15) : (r + ih - 15);
            bool ok = (bidx >= 0) && (bidx <= 13) && (r < 30);
            int src = (lane < 32) ? min(13, max(0, bidx)) : 16 + min(13, max(0, bidx));
            float g = __shfl(bs, src, 64);
            val = ok ? g : 0.f;
            if (r == 0) val += pcls;
        }
        int col = (lane < 32) ? (208 + lane) : (240 + (lane - 32));
        St[m * 292 + col] = val;
    }
    __syncthreads();

    // ---- phase 2: O = P_aug @ Vt^T (2-pass: P exact hi/lo, V single bf16)
    {
        f32x4 oacc[2] = {(f32x4){0, 0, 0, 0}, (f32x4){0, 0, 0, 0}};
        for (int ks = 0; ks < 9; ++ks) {
            int k0 = ks * 32;
            const float* ap = &St[(mr0 + l16) * 292 + k0 + quad * 8];
            float4 a0 = *(const float4*)ap;
            float4 a1 = *(const float4*)(ap + 4);
            float av[8] = {a0.x, a0.y, a0.z, a0.w, a1.x, a1.y, a1.z, a1.w};
            short8 ph, pl;
            #pragma unroll
            for (int e = 0; e < 8; ++e) {
                float f = av[e];
                u16 hs = f2bf(f);
                u16 ls = f2bf(f - bf2f(hs));
                ph[e] = (short)hs; pl[e] = (short)ls;
            }
            #pragma unroll
            for (int s = 0; s < 2; ++s) {
                int nf = nh * 2 + s;
                short8 vb = *(const short8*)&Vts[(nf * 16 + l16) * 296 + k0 + quad * 8];
                oacc[s] = MFMA(ph, vb, oacc[s], 0, 0, 0);
                oacc[s] = MFMA(pl, vb, oacc[s], 0, 0, 0);
            }
        }
        int b = bh / 12, h = bh - b * 12;
        #pragma unroll
        for (int s = 0; s < 2; ++s) {
            int d = (nh * 2 + s) * 16 + l16;
            #pragma unroll
            for (int r = 0; r < 4; ++r) {
                int m = mr0 + quad * 4 + r;
                int i = I0 + m;
                if (i < 197) {
                    float f = oacc[s][r];
                    u16 hs = f2bf(f);
                    u16 ls = f2bf(f - bf2f(hs));
                    size_t addr = ((size_t)(b * 197 + i)) * 768 + h * 64 + d;
                    oh[addr] = hs;
                    ol[addr] = ls;
                }
            }
        }
    }
}

// ---------------------------------------------------------------------------
extern "C" void kernel_launch(void* const* d_in, const int* in_sizes, int n_in,
                              void* d_out, int out_size, void* d_ws, size_t ws_size,
                              hipStream_t stream)
{
    const float* x   = (const float*)d_in[0];
    const float* wq  = (const float*)d_in[1];
    const float* bq  = (const float*)d_in[2];
    const float* wk  = (const float*)d_in[3];
    const float* bk  = (const float*)d_in[4];
    const float* wv  = (const float*)d_in[5];
    const float* bv  = (const float*)d_in[6];
    const float* wp  = (const float*)d_in[7];
    const float* bp  = (const float*)d_in[8];
    const float* rkv = (const float*)d_in[9];
    const float* rkh = (const float*)d_in[10];
    const float* rvv = (const float*)d_in[11];
    const float* rvh = (const float*)d_in[12];
    float* out = (float*)d_out;

    const size_t SZX = (size_t)12608 * 768;   // 9,682,944 elems
    const size_t SZW = (size_t)768 * 768;

    u16* xh = (u16*)d_ws;
    u16* xl = xh + SZX;
    u16* qh_ = xl + SZX;
    u16* ql_ = qh_ + SZX;
    u16* kh_ = ql_ + SZX;
    u16* kl_ = kh_ + SZX;
    u16* vh_ = kl_ + SZX;
    u16* wt  = vh_ + SZX;
    u16* wqh = wt,           *wql = wt + SZW;
    u16* wkh = wt + 2 * SZW, *wkl = wt + 3 * SZW;
    u16* wvh = wt + 4 * SZW, *wvl = wt + 5 * SZW;
    u16* wph = wt + 6 * SZW, *wpl = wt + 7 * SZW;
    u16* tkh = wt + 8 * SZW;
    u16* tkl = tkh + 4096;
    u16* rth = tkl + 4096;
    u16* oh_ = xh;   // overlay: x dead after QKV projection
    u16* ol_ = xl;

    prep_split_x<<<4728, 256, 0, stream>>>(x, xh, xl);
    prep_w<<<dim3(12, 12, 4), 256, 0, stream>>>(wq, wk, wv, wp,
        wqh, wql, wkh, wkl, wvh, wvl, wph, wpl);
    prep_tabs<<<1, 256, 0, stream>>>(rkv, rkh, rvv, rvh, tkh, tkl, rth);

    gemm_bf16<<<dim3(6, 99, 3), 256, 0, stream>>>(
        xh, xl, wqh, wql, wkh, wkl, wvh, wvl, bq, bk, bv,
        qh_, ql_, kh_, kl_, vh_, nullptr, nullptr, 0);

    attn_mfma<<<dim3(4, 768), 512, 0, stream>>>(
        qh_, ql_, kh_, kl_, vh_, tkh, tkl, rth, oh_, ol_);

    gemm_bf16<<<dim3(6, 99, 1), 256, 0, stream>>>(
        oh_, ol_, wph, wpl, wph, wpl, wph, wpl, bp, bp, bp,
        nullptr, nullptr, nullptr, nullptr, nullptr, nullptr, out, 1);
}

// Round 4
// 578.646 us; speedup vs baseline: 5.4614x; 1.0511x over previous
//
#include <hip/hip_runtime.h>
#include <math.h>

#define SCALE_ 0.125f

typedef unsigned short u16;
typedef __attribute__((ext_vector_type(8))) short short8;
typedef __attribute__((ext_vector_type(4))) float f32x4;
#define MFMA __builtin_amdgcn_mfma_f32_16x16x32_bf16

__device__ __forceinline__ u16 f2bf(float f) {
    unsigned int u = __float_as_uint(f);
    unsigned int r = (u + 0x7fffu + ((u >> 16) & 1u)) >> 16;
    return (u16)r;
}
__device__ __forceinline__ float bf2f(u16 h) {
    return __uint_as_float(((unsigned int)h) << 16);
}
__device__ __forceinline__ void gload16(const u16* g, u16* l) {
    __builtin_amdgcn_global_load_lds(
        (const __attribute__((address_space(1))) void*)g,
        (__attribute__((address_space(3))) void*)l, 16, 0, 0);
}
__device__ __forceinline__ short8 ld_s8(const u16* p) {
    short8 v; *(uint4*)&v = *(const uint4*)p; return v;
}

// ---------------------------------------------------------------------------
// prep: split x into hi/lo bf16
// ---------------------------------------------------------------------------
__global__ void prep_split_x(const float* __restrict__ x, u16* __restrict__ xh,
                             u16* __restrict__ xl) {
    size_t idx = ((size_t)blockIdx.x * 256 + threadIdx.x) * 8;
    float4 a = *(const float4*)(x + idx), b = *(const float4*)(x + idx + 4);
    float f[8] = {a.x, a.y, a.z, a.w, b.x, b.y, b.z, b.w};
    u16 hs[8], ls[8];
    #pragma unroll
    for (int e = 0; e < 8; ++e) {
        hs[e] = f2bf(f[e]);
        ls[e] = f2bf(f[e] - bf2f(hs[e]));
    }
    *(uint4*)(xh + idx) = *(uint4*)hs;
    *(uint4*)(xl + idx) = *(uint4*)ls;
}

// ---------------------------------------------------------------------------
// prep: transpose + split weights: Wt[n][k] = W[k][n], hi/lo bf16
// ---------------------------------------------------------------------------
__global__ void prep_w(const float* __restrict__ w0, const float* __restrict__ w1,
                       const float* __restrict__ w2, const float* __restrict__ w3,
                       u16* o0h, u16* o0l, u16* o1h, u16* o1l,
                       u16* o2h, u16* o2l, u16* o3h, u16* o3l) {
    const float* W; u16* oh; u16* ol;
    if (blockIdx.z == 0)      { W = w0; oh = o0h; ol = o0l; }
    else if (blockIdx.z == 1) { W = w1; oh = o1h; ol = o1l; }
    else if (blockIdx.z == 2) { W = w2; oh = o2h; ol = o2l; }
    else                      { W = w3; oh = o3h; ol = o3l; }

    __shared__ float t[64 * 68];
    int k0 = blockIdx.y * 64, n0 = blockIdx.x * 64;
    int tid = threadIdx.x;
    #pragma unroll
    for (int rr = 0; rr < 4; ++rr) {
        int r = (tid >> 4) + rr * 16;
        int c = (tid & 15) * 4;
        *(float4*)&t[r * 68 + c] = *(const float4*)(W + (size_t)(k0 + r) * 768 + n0 + c);
    }
    __syncthreads();
    int n = tid >> 2, kc = (tid & 3) * 16;
    u16 hs[16], ls[16];
    #pragma unroll
    for (int e = 0; e < 16; ++e) {
        float f = t[(kc + e) * 68 + n];
        hs[e] = f2bf(f);
        ls[e] = f2bf(f - bf2f(hs[e]));
    }
    size_t o = (size_t)(n0 + n) * 768 + k0 + kc;
    *(uint4*)(oh + o) = *(uint4*)hs;  *(uint4*)(oh + o + 8) = *(uint4*)(hs + 8);
    *(uint4*)(ol + o) = *(uint4*)ls;  *(uint4*)(ol + o + 8) = *(uint4*)(ls + 8);
}

// ---------------------------------------------------------------------------
// prep: tables. Tk[r][d] (r: 0..29 rkv, 32..61 rkh, zeros elsewhere) hi/lo;
// rth[d][r] = rel_v tables transposed, bf16 hi only.
// ---------------------------------------------------------------------------
__global__ void prep_tabs(const float* __restrict__ rkv, const float* __restrict__ rkh,
                          const float* __restrict__ rvv, const float* __restrict__ rvh,
                          u16* tkh, u16* tkl, u16* rth) {
    for (int idx = threadIdx.x; idx < 4096; idx += 256) {
        int r = idx >> 6, d = idx & 63;
        float tv = 0.f;
        if (r < 30) tv = rkv[r * 64 + d];
        else if (r >= 32 && r < 62) tv = rkh[(r - 32) * 64 + d];
        u16 hs = f2bf(tv);
        tkh[idx] = hs;
        tkl[idx] = f2bf(tv - bf2f(hs));
        int dd = idx >> 6, rr = idx & 63;
        float vv = 0.f;
        if (rr < 30) vv = rvv[rr * 64 + dd];
        else if (rr >= 32 && rr < 62) vv = rvh[(rr - 32) * 64 + dd];
        rth[idx] = f2bf(vv);
    }
}

// ---------------------------------------------------------------------------
// prep: fill constant part of the V-augmented matrix vt[bh][d][key-dim 288]:
// cols 197..207 zero, 208..271 rel_v tables ([d][r] from rth), 272..287 zero.
// (cols 0..196 are written by the QKV gemm epilogue.)
// ---------------------------------------------------------------------------
__global__ void prep_vt(const u16* __restrict__ rth, u16* __restrict__ vtp) {
    u16* vb = vtp + (size_t)blockIdx.x * 64 * 288;
    for (int t = threadIdx.x; t < 64 * 91; t += 256) {
        int d = t / 91;
        int c = 197 + (t - d * 91);
        u16 val = 0;
        if (c >= 208 && c < 272) val = rth[d * 64 + (c - 208)];
        vb[d * 288 + c] = val;
    }
}

// ---------------------------------------------------------------------------
// Split-bf16 MFMA GEMM with global_load_lds staging (m97 structure).
// C(12608,768) = A @ B + bias; A hi/lo row-major, B as Bt[n][k] hi/lo.
// kind 0 (QKV): z=0 -> q hi/lo scatter (B,H,N,64); z=1 -> k hi/lo scatter;
//               z=2 -> v into vt[bh][d][288] transposed (hi only).
// kind 1 (proj): plain fp32 output.
// ---------------------------------------------------------------------------
__global__ __launch_bounds__(256, 3) void gemm_bf16(
    const u16* __restrict__ Ah, const u16* __restrict__ Al,
    const u16* __restrict__ B0h, const u16* __restrict__ B0l,
    const u16* __restrict__ B1h, const u16* __restrict__ B1l,
    const u16* __restrict__ B2h, const u16* __restrict__ B2l,
    const float* __restrict__ bias0, const float* __restrict__ bias1,
    const float* __restrict__ bias2,
    u16* qoh, u16* qol, u16* koh, u16* kol, u16* vtp,
    float* outf, int kind)
{
    const int z = blockIdx.z;
    const u16* Bh = B0h; const u16* Bl = B0l; const float* bias = bias0;
    if (z == 1) { Bh = B1h; Bl = B1l; bias = bias1; }
    else if (z == 2) { Bh = B2h; Bl = B2l; bias = bias2; }

    __shared__ u16 Ahs[128 * 32];
    __shared__ u16 Als[128 * 32];
    __shared__ u16 Bhs[128 * 32];
    __shared__ u16 Bls[128 * 32];

    const int tid = threadIdx.x;
    const int m0 = blockIdx.y * 128, n0 = blockIdx.x * 128;
    const int w = tid >> 6, lane = tid & 63, quad = lane >> 4, l16 = lane & 15;
    const int wm = (w >> 1) * 64, wn = (w & 1) * 64;
    const int srow = lane >> 2;        // 0..15 row within 16-row chunk
    const int scol = (lane & 3) * 8;   // u16 col 0,8,16,24

    f32x4 acc[4][4];
    #pragma unroll
    for (int a = 0; a < 4; ++a)
        #pragma unroll
        for (int b = 0; b < 4; ++b) acc[a][b] = (f32x4){0, 0, 0, 0};

    for (int kt = 0; kt < 768; kt += 32) {
        __syncthreads();   // previous iteration's frag reads done
        #pragma unroll
        for (int p = 0; p < 2; ++p) {
            int r = p * 64 + w * 16 + srow;
            int arow = m0 + r;
            u16* la  = &Ahs[(p * 64 + w * 16) * 32];
            u16* lal = &Als[(p * 64 + w * 16) * 32];
            u16* lb  = &Bhs[(p * 64 + w * 16) * 32];
            u16* lbl = &Bls[(p * 64 + w * 16) * 32];
            if (arow < 12608) {
                gload16(Ah + (size_t)arow * 768 + kt + scol, la);
                gload16(Al + (size_t)arow * 768 + kt + scol, lal);
            }
            gload16(Bh + (size_t)(n0 + r) * 768 + kt + scol, lb);
            gload16(Bl + (size_t)(n0 + r) * 768 + kt + scol, lbl);
        }
        __syncthreads();   // async loads landed

        short8 ah[4], al[4];
        #pragma unroll
        for (int mi = 0; mi < 4; ++mi) {
            ah[mi] = ld_s8(&Ahs[(wm + mi * 16 + l16) * 32 + quad * 8]);
            al[mi] = ld_s8(&Als[(wm + mi * 16 + l16) * 32 + quad * 8]);
        }
        #pragma unroll
        for (int ni = 0; ni < 4; ++ni) {
            short8 bhf = ld_s8(&Bhs[(wn + ni * 16 + l16) * 32 + quad * 8]);
            short8 blf = ld_s8(&Bls[(wn + ni * 16 + l16) * 32 + quad * 8]);
            #pragma unroll
            for (int mi = 0; mi < 4; ++mi) {
                acc[mi][ni] = MFMA(ah[mi], bhf, acc[mi][ni], 0, 0, 0);
                acc[mi][ni] = MFMA(ah[mi], blf, acc[mi][ni], 0, 0, 0);
                acc[mi][ni] = MFMA(al[mi], bhf, acc[mi][ni], 0, 0, 0);
            }
        }
    }

    #pragma unroll
    for (int mi = 0; mi < 4; ++mi) {
        #pragma unroll
        for (int r = 0; r < 4; ++r) {
            int gr = m0 + wm + mi * 16 + quad * 4 + r;
            if (gr >= 12608) continue;
            int bb = gr / 197;
            int ii = gr - bb * 197;
            #pragma unroll
            for (int ni = 0; ni < 4; ++ni) {
                int gc = n0 + wn + ni * 16 + l16;
                float val = acc[mi][ni][r] + bias[gc];
                if (kind == 1) {
                    outf[(size_t)gr * 768 + gc] = val;
                } else {
                    int h = gc >> 6, d = gc & 63;
                    if (z == 2) {
                        vtp[((size_t)(bb * 12 + h) * 64 + d) * 288 + ii] = f2bf(val);
                    } else {
                        u16* OH = z ? koh : qoh;
                        u16* OL = z ? kol : qol;
                        size_t addr = ((size_t)(bb * 12 + h) * 197 + ii) * 64 + d;
                        u16 hs = f2bf(val);
                        OH[addr] = hs;
                        OL[addr] = f2bf(val - bf2f(hs));
                    }
                }
            }
        }
    }
}

// ---------------------------------------------------------------------------
// Fused attention v3: register-resident scores, no Q/K/V LDS staging.
// Per block (qtile64, bh), 512 thr, 8 waves (mf=w>>1 rows, nh=w&1 col-half).
// Phase 0: Tvh = Q.Tk^T (3-pass, frags direct from global) -> LDS fp32.
// Phase 1: S = Q.K^T (3-pass, K frags direct from global) -> registers.
// In-register bias + scale; cross-wave softmax partials via red[]; p (unnorm)
// -> Ph bf16. Hist phase: band sums from Ph -> Wv/Wh cols 208..271 (unnorm).
// Phase 2: O = Ph @ vt^T (K=288, B-frags direct from global vt), scaled by
// 1/rowsum in the epilogue; output hi/lo bf16 for the proj GEMM.
// LDS: Ph 64x296 u16 (37.9KB) + Tvh 64x68 f32 (17.4KB) + red 1KB -> 2 blk/CU.
// ---------------------------------------------------------------------------
__global__ __launch_bounds__(512, 4) void attn_mfma(
    const u16* __restrict__ qh, const u16* __restrict__ ql,
    const u16* __restrict__ kh, const u16* __restrict__ kl,
    const u16* __restrict__ tkh, const u16* __restrict__ tkl,
    const u16* __restrict__ vt,
    u16* __restrict__ oh, u16* __restrict__ ol)
{
    __shared__ u16 Ph[64 * 296];
    __shared__ float Tvh[64 * 68];
    __shared__ float red[64 * 4];   // [m][max0,max1,sum0,sum1]

    const int qt = blockIdx.x, bh = blockIdx.y;
    const int I0 = qt * 64;
    const int tid = threadIdx.x;
    const int w = tid >> 6, lane = tid & 63, quad = lane >> 4, l16 = lane & 15;
    const int mf = w >> 1, nh = w & 1;
    const int mr0 = mf * 16;
    const size_t base = (size_t)bh * 197 * 64;
    const uint4 z4 = make_uint4(0, 0, 0, 0);

    // ---- Q A-frags direct from global (zero for i >= 197)
    short8 qah[2], qal[2];
    {
        int i = I0 + mr0 + l16;
        bool ok = i < 197;
        const u16* qp  = qh + base + (size_t)i * 64 + quad * 8;
        const u16* qpl = ql + base + (size_t)i * 64 + quad * 8;
        #pragma unroll
        for (int kb = 0; kb < 2; ++kb) {
            uint4 a = ok ? *(const uint4*)(qp + kb * 32) : z4;
            uint4 b = ok ? *(const uint4*)(qpl + kb * 32) : z4;
            *(uint4*)&qah[kb] = a;
            *(uint4*)&qal[kb] = b;
        }
    }

    // ---- phase 0: Tvh (cols nh*32 .. nh*32+31)
    #pragma unroll
    for (int s2 = 0; s2 < 2; ++s2) {
        int c = (nh * 2 + s2) * 16 + l16;
        f32x4 acc = (f32x4){0, 0, 0, 0};
        #pragma unroll
        for (int kb = 0; kb < 2; ++kb) {
            short8 th = ld_s8(tkh + c * 64 + kb * 32 + quad * 8);
            short8 tl = ld_s8(tkl + c * 64 + kb * 32 + quad * 8);
            acc = MFMA(qah[kb], th, acc, 0, 0, 0);
            acc = MFMA(qah[kb], tl, acc, 0, 0, 0);
            acc = MFMA(qal[kb], th, acc, 0, 0, 0);
        }
        #pragma unroll
        for (int r = 0; r < 4; ++r)
            Tvh[(mr0 + quad * 4 + r) * 68 + c] = acc[r];
    }

    // ---- phase 1: S = Q.K^T (cols nh*112 .. ; 7 frags, last of nh=1 void)
    f32x4 sacc[7];
    #pragma unroll
    for (int s = 0; s < 7; ++s) sacc[s] = (f32x4){0, 0, 0, 0};
    #pragma unroll
    for (int s = 0; s < 7; ++s) {
        int j = (nh * 7 + s) * 16 + l16;
        bool ok = j < 197;
        const u16* kp  = kh + base + (size_t)j * 64 + quad * 8;
        const u16* kpl = kl + base + (size_t)j * 64 + quad * 8;
        f32x4 c = sacc[s];
        #pragma unroll
        for (int kb = 0; kb < 2; ++kb) {
            uint4 a = ok ? *(const uint4*)(kp + kb * 32) : z4;
            uint4 b = ok ? *(const uint4*)(kpl + kb * 32) : z4;
            short8 kbh, kbl;
            *(uint4*)&kbh = a;
            *(uint4*)&kbl = b;
            c = MFMA(qah[kb], kbh, c, 0, 0, 0);
            c = MFMA(qah[kb], kbl, c, 0, 0, 0);
            c = MFMA(qal[kb], kbh, c, 0, 0, 0);
        }
        sacc[s] = c;
    }
    __syncthreads();   // Tvh visible

    // ---- in-register bias + scale
    float sval[7][4];
    int jj[7];
    #pragma unroll
    for (int s = 0; s < 7; ++s) jj[s] = (nh * 7 + s) * 16 + l16;
    int ivA[4], ihA[4], iA[4];
    #pragma unroll
    for (int r = 0; r < 4; ++r) {
        int i = I0 + mr0 + quad * 4 + r;
        int qi = i - 1;
        int iv = qi / 14;
        ivA[r] = iv; ihA[r] = qi - iv * 14; iA[r] = i;
    }
    #pragma unroll
    for (int s = 0; s < 7; ++s) {
        int j = jj[s];
        if (j < 197) {
            int kj = j - 1;
            int jv = kj / 14;
            int jh2 = kj - jv * 14;
            #pragma unroll
            for (int r = 0; r < 4; ++r) {
                int m = mr0 + quad * 4 + r;
                int fv = 0, fh = 0;
                if (iA[r] > 0 && j > 0) {
                    int dv = jv - ivA[r]; dv = min(14, max(-14, dv));
                    int dh = jh2 - ihA[r]; dh = min(14, max(-14, dh));
                    fv = dv + 15; fh = dh + 15;
                }
                sval[s][r] = (sacc[s][r] + Tvh[m * 68 + fv] + Tvh[m * 68 + 32 + fh]) * SCALE_;
            }
        } else {
            #pragma unroll
            for (int r = 0; r < 4; ++r) sval[s][r] = -1e30f;
        }
    }

    // ---- partial row max -> red
    #pragma unroll
    for (int r = 0; r < 4; ++r) {
        float mx = sval[0][r];
        #pragma unroll
        for (int s = 1; s < 7; ++s) mx = fmaxf(mx, sval[s][r]);
        #pragma unroll
        for (int off = 1; off < 16; off <<= 1) mx = fmaxf(mx, __shfl_xor(mx, off, 64));
        if (l16 == 0) red[(mr0 + quad * 4 + r) * 4 + nh] = mx;
    }
    __syncthreads();

    // ---- exp + partial sums + write Ph (unnormalized p)
    #pragma unroll
    for (int r = 0; r < 4; ++r) {
        int m = mr0 + quad * 4 + r;
        float M = fmaxf(red[m * 4], red[m * 4 + 1]);
        float sum = 0.f;
        #pragma unroll
        for (int s = 0; s < 7; ++s) {
            float p = (jj[s] < 197) ? __expf(sval[s][r] - M) : 0.f;
            sval[s][r] = p;
            sum += p;
        }
        #pragma unroll
        for (int off = 1; off < 16; off <<= 1) sum += __shfl_xor(sum, off, 64);
        if (l16 == 0) red[m * 4 + 2 + nh] = sum;
    }
    #pragma unroll
    for (int s = 0; s < 7; ++s) {
        int j = jj[s];
        if (j < 208) {
            #pragma unroll
            for (int r = 0; r < 4; ++r)
                Ph[(mr0 + quad * 4 + r) * 296 + j] = f2bf(sval[s][r]);
        }
    }
    __syncthreads();   // p cols + sums ready

    // ---- histogram phase: wave w owns rows w*8..w*8+7
    for (int q8 = 0; q8 < 8; ++q8) {
        int m = w * 8 + q8;
        int i = I0 + m;
        float bs = 0.f;
        if (lane < 14) {
            #pragma unroll
            for (int c = 0; c < 14; ++c) bs += bf2f(Ph[m * 296 + 1 + lane * 14 + c]);
        } else if (lane >= 16 && lane < 30) {
            int c = lane - 16;
            #pragma unroll
            for (int b = 0; b < 14; ++b) bs += bf2f(Ph[m * 296 + 1 + b * 14 + c]);
        }
        float pcls = bf2f(Ph[m * 296]);
        float val;
        if (i == 0) {
            float lsum = red[m * 4 + 2] + red[m * 4 + 3];
            val = ((lane & 31) == 0) ? lsum : 0.f;
        } else {
            int qi = i - 1;
            int iv = qi / 14, ih = qi - (qi / 14) * 14;
            int r = lane & 31;
            int bidx = (lane < 32) ? (r + iv - 15) : (r + ih - 15);
            bool ok = (bidx >= 0) && (bidx <= 13) && (r < 30);
            int src = (lane < 32) ? min(13, max(0, bidx)) : 16 + min(13, max(0, bidx));
            float g = __shfl(bs, src, 64);
            val = ok ? g : 0.f;
            if (r == 0) val += pcls;
        }
        int col = (lane < 32) ? (208 + lane) : (240 + (lane - 32));
        Ph[m * 296 + col] = f2bf(val);
    }
    // zero pad cols 272..287
    for (int t = tid; t < 64 * 16; t += 512)
        Ph[(t >> 4) * 296 + 272 + (t & 15)] = 0;
    __syncthreads();   // Ph complete

    // ---- phase 2: O = Ph @ vt^T (K=288), B-frags from global
    {
        f32x4 oacc[2] = {(f32x4){0, 0, 0, 0}, (f32x4){0, 0, 0, 0}};
        const u16* vb = vt + (size_t)bh * 64 * 288;
        #pragma unroll
        for (int ks = 0; ks < 9; ++ks) {
            short8 ap = ld_s8(&Ph[(mr0 + l16) * 296 + ks * 32 + quad * 8]);
            #pragma unroll
            for (int sd = 0; sd < 2; ++sd) {
                int d = (nh * 2 + sd) * 16 + l16;
                short8 bv = ld_s8(vb + (size_t)d * 288 + ks * 32 + quad * 8);
                oacc[sd] = MFMA(ap, bv, oacc[sd], 0, 0, 0);
            }
        }
        int b = bh / 12, h = bh - b * 12;
        float rl[4];
        #pragma unroll
        for (int r = 0; r < 4; ++r) {
            int m = mr0 + quad * 4 + r;
            rl[r] = 1.f / (red[m * 4 + 2] + red[m * 4 + 3]);
        }
        #pragma unroll
        for (int sd = 0; sd < 2; ++sd) {
            int d = (nh * 2 + sd) * 16 + l16;
            #pragma unroll
            for (int r = 0; r < 4; ++r) {
                int i = I0 + mr0 + quad * 4 + r;
                if (i < 197) {
                    float val = oacc[sd][r] * rl[r];
                    u16 hs = f2bf(val);
                    size_t addr = ((size_t)(b * 197 + i)) * 768 + h * 64 + d;
                    oh[addr] = hs;
                    ol[addr] = f2bf(val - bf2f(hs));
                }
            }
        }
    }
}

// ---------------------------------------------------------------------------
extern "C" void kernel_launch(void* const* d_in, const int* in_sizes, int n_in,
                              void* d_out, int out_size, void* d_ws, size_t ws_size,
                              hipStream_t stream)
{
    const float* x   = (const float*)d_in[0];
    const float* wq  = (const float*)d_in[1];
    const float* bq  = (const float*)d_in[2];
    const float* wk  = (const float*)d_in[3];
    const float* bk  = (const float*)d_in[4];
    const float* wv  = (const float*)d_in[5];
    const float* bv  = (const float*)d_in[6];
    const float* wp  = (const float*)d_in[7];
    const float* bp  = (const float*)d_in[8];
    const float* rkv = (const float*)d_in[9];
    const float* rkh = (const float*)d_in[10];
    const float* rvv = (const float*)d_in[11];
    const float* rvh = (const float*)d_in[12];
    float* out = (float*)d_out;

    const size_t SZX = (size_t)12608 * 768;
    const size_t SZW = (size_t)768 * 768;
    const size_t SZVT = (size_t)768 * 64 * 288;

    u16* xh = (u16*)d_ws;
    u16* xl = xh + SZX;
    u16* qh_ = xl + SZX;
    u16* ql_ = qh_ + SZX;
    u16* kh_ = ql_ + SZX;
    u16* kl_ = kh_ + SZX;
    u16* vt  = kl_ + SZX;
    u16* wt  = vt + SZVT;
    u16* wqh = wt,           *wql = wt + SZW;
    u16* wkh = wt + 2 * SZW, *wkl = wt + 3 * SZW;
    u16* wvh = wt + 4 * SZW, *wvl = wt + 5 * SZW;
    u16* wph = wt + 6 * SZW, *wpl = wt + 7 * SZW;
    u16* tkh = wt + 8 * SZW;
    u16* tkl = tkh + 4096;
    u16* rth = tkl + 4096;
    u16* oh_ = xh;   // overlay: x dead after QKV projection
    u16* ol_ = xl;

    prep_split_x<<<4728, 256, 0, stream>>>(x, xh, xl);
    prep_w<<<dim3(12, 12, 4), 256, 0, stream>>>(wq, wk, wv, wp,
        wqh, wql, wkh, wkl, wvh, wvl, wph, wpl);
    prep_tabs<<<1, 256, 0, stream>>>(rkv, rkh, rvv, rvh, tkh, tkl, rth);
    prep_vt<<<768, 256, 0, stream>>>(rth, vt);

    gemm_bf16<<<dim3(6, 99, 3), 256, 0, stream>>>(
        xh, xl, wqh, wql, wkh, wkl, wvh, wvl, bq, bk, bv,
        qh_, ql_, kh_, kl_, vt, nullptr, 0);

    attn_mfma<<<dim3(4, 768), 512, 0, stream>>>(
        qh_, ql_, kh_, kl_, tkh, tkl, vt, oh_, ol_);

    gemm_bf16<<<dim3(6, 99, 1), 256, 0, stream>>>(
        oh_, ol_, wph, wpl, wph, wpl, wph, wpl, bp, bp, bp,
        nullptr, nullptr, nullptr, nullptr, nullptr, out, 1);
}

// Round 5
// 398.371 us; speedup vs baseline: 7.9329x; 1.4525x over previous
//
#include <hip/hip_runtime.h>
#include <math.h>

#define SCALE_ 0.125f

typedef unsigned short u16;
typedef __attribute__((ext_vector_type(8))) _Float16 half8;
typedef __attribute__((ext_vector_type(4))) float f32x4;
#define MFMA_H __builtin_amdgcn_mfma_f32_16x16x32_f16

__device__ __forceinline__ u16 f2h(float f) {
    union { _Float16 h; u16 u; } v; v.h = (_Float16)f; return v.u;
}
__device__ __forceinline__ float h2f(u16 u) {
    union { _Float16 h; u16 u; } v; v.u = u; return (float)v.h;
}
__device__ __forceinline__ void gload16(const u16* g, u16* l) {
    __builtin_amdgcn_global_load_lds(
        (const __attribute__((address_space(1))) void*)g,
        (__attribute__((address_space(3))) void*)l, 16, 0, 0);
}
__device__ __forceinline__ half8 ld_h8(const u16* p) {
    return *(const half8*)p;
}

// ---------------------------------------------------------------------------
// prep: x -> f16
// ---------------------------------------------------------------------------
__global__ void prep_half_x(const float* __restrict__ x, u16* __restrict__ xh) {
    size_t idx = ((size_t)blockIdx.x * 256 + threadIdx.x) * 8;
    float4 a = *(const float4*)(x + idx), b = *(const float4*)(x + idx + 4);
    float f[8] = {a.x, a.y, a.z, a.w, b.x, b.y, b.z, b.w};
    u16 hs[8];
    #pragma unroll
    for (int e = 0; e < 8; ++e) hs[e] = f2h(f[e]);
    *(uint4*)(xh + idx) = *(uint4*)hs;
}

// ---------------------------------------------------------------------------
// prep: transpose weights: Wt[n][k] = W[k][n], f16
// ---------------------------------------------------------------------------
__global__ void prep_w(const float* __restrict__ w0, const float* __restrict__ w1,
                       const float* __restrict__ w2, const float* __restrict__ w3,
                       u16* o0, u16* o1, u16* o2, u16* o3) {
    const float* W; u16* oh;
    if (blockIdx.z == 0)      { W = w0; oh = o0; }
    else if (blockIdx.z == 1) { W = w1; oh = o1; }
    else if (blockIdx.z == 2) { W = w2; oh = o2; }
    else                      { W = w3; oh = o3; }

    __shared__ float t[64 * 68];
    int k0 = blockIdx.y * 64, n0 = blockIdx.x * 64;
    int tid = threadIdx.x;
    #pragma unroll
    for (int rr = 0; rr < 4; ++rr) {
        int r = (tid >> 4) + rr * 16;
        int c = (tid & 15) * 4;
        *(float4*)&t[r * 68 + c] = *(const float4*)(W + (size_t)(k0 + r) * 768 + n0 + c);
    }
    __syncthreads();
    int n = tid >> 2, kc = (tid & 3) * 16;
    u16 hs[16];
    #pragma unroll
    for (int e = 0; e < 16; ++e) hs[e] = f2h(t[(kc + e) * 68 + n]);
    size_t o = (size_t)(n0 + n) * 768 + k0 + kc;
    *(uint4*)(oh + o) = *(uint4*)hs;
    *(uint4*)(oh + o + 8) = *(uint4*)(hs + 8);
}

// ---------------------------------------------------------------------------
// prep: tables. tk[r][d] f16 (r: 0..29 rkv, 32..61 rkh, zeros elsewhere);
// rth[d][r] = rel_v tables transposed, f16.
// ---------------------------------------------------------------------------
__global__ void prep_tabs(const float* __restrict__ rkv, const float* __restrict__ rkh,
                          const float* __restrict__ rvv, const float* __restrict__ rvh,
                          u16* tk, u16* rth) {
    for (int idx = threadIdx.x; idx < 4096; idx += 256) {
        int r = idx >> 6, d = idx & 63;
        float tv = 0.f;
        if (r < 30) tv = rkv[r * 64 + d];
        else if (r >= 32 && r < 62) tv = rkh[(r - 32) * 64 + d];
        tk[idx] = f2h(tv);
        int dd = idx >> 6, rr = idx & 63;
        float vv = 0.f;
        if (rr < 30) vv = rvv[rr * 64 + dd];
        else if (rr >= 32 && rr < 62) vv = rvh[(rr - 32) * 64 + dd];
        rth[idx] = f2h(vv);
    }
}

// ---------------------------------------------------------------------------
// prep: constant part of vt[bh][d][288]: cols 197..207 zero, 208..271 rel_v
// ([d][r] from rth), 272..287 zero. (cols 0..196 from QKV gemm z=2.)
// ---------------------------------------------------------------------------
__global__ void prep_vt(const u16* __restrict__ rth, u16* __restrict__ vtp) {
    u16* vb = vtp + (size_t)blockIdx.x * 64 * 288;
    for (int t = threadIdx.x; t < 64 * 91; t += 256) {
        int d = t / 91;
        int c = 197 + (t - d * 91);
        u16 val = 0;
        if (c >= 208 && c < 272) val = rth[d * 64 + (c - 208)];
        vb[d * 288 + c] = val;
    }
}

// ---------------------------------------------------------------------------
// Single-pass f16 MFMA GEMM (m97 staging + XOR LDS swizzle).
// C(12608,768) = A @ B + bias; A f16 row-major, B as Bt[n][k] f16.
// kind 0 (QKV): z=0 -> q scatter (B,H,N,64); z=1 -> k scatter;
//               z=2 -> v transposed into vt[bh][d][288].
// kind 1 (proj): plain fp32 output.
// LDS swizzle: global chunk c of row r is stored at LDS chunk c ^ ((r>>1)&3)
// (applied by permuting the global source per lane; global_load_lds dest is
// the packed wave-uniform base + lane*16).
// ---------------------------------------------------------------------------
__global__ __launch_bounds__(256, 4) void gemm_f16(
    const u16* __restrict__ Ah,
    const u16* __restrict__ B0, const u16* __restrict__ B1, const u16* __restrict__ B2,
    const float* __restrict__ bias0, const float* __restrict__ bias1,
    const float* __restrict__ bias2,
    u16* qo, u16* ko, u16* vtp, float* outf, int kind)
{
    const int z = blockIdx.z;
    const u16* Bt = B0; const float* bias = bias0;
    if (z == 1) { Bt = B1; bias = bias1; }
    else if (z == 2) { Bt = B2; bias = bias2; }

    __shared__ u16 Ahs[128 * 32];
    __shared__ u16 Bhs[128 * 32];

    const int tid = threadIdx.x;
    const int m0 = blockIdx.y * 128, n0 = blockIdx.x * 128;
    const int w = tid >> 6, lane = tid & 63, quad = lane >> 4, l16 = lane & 15;
    const int wm = (w >> 1) * 64, wn = (w & 1) * 64;
    const int srow = lane >> 2;                              // 0..15
    const int scol = ((lane & 3) ^ ((srow >> 1) & 3)) * 8;   // swizzled source chunk
    const int fsw = ((l16 >> 1) & 3);                        // frag-read swizzle

    f32x4 acc[4][4];
    #pragma unroll
    for (int a = 0; a < 4; ++a)
        #pragma unroll
        for (int b = 0; b < 4; ++b) acc[a][b] = (f32x4){0, 0, 0, 0};

    for (int kt = 0; kt < 768; kt += 32) {
        __syncthreads();
        #pragma unroll
        for (int p = 0; p < 2; ++p) {
            int r = p * 64 + w * 16 + srow;
            int arow = m0 + r;
            u16* la = &Ahs[(p * 64 + w * 16) * 32];
            u16* lb = &Bhs[(p * 64 + w * 16) * 32];
            if (arow < 12608) gload16(Ah + (size_t)arow * 768 + kt + scol, la);
            gload16(Bt + (size_t)(n0 + r) * 768 + kt + scol, lb);
        }
        __syncthreads();

        half8 ah[4];
        #pragma unroll
        for (int mi = 0; mi < 4; ++mi)
            ah[mi] = ld_h8(&Ahs[(wm + mi * 16 + l16) * 32 + (quad ^ fsw) * 8]);
        #pragma unroll
        for (int ni = 0; ni < 4; ++ni) {
            half8 bf = ld_h8(&Bhs[(wn + ni * 16 + l16) * 32 + (quad ^ fsw) * 8]);
            #pragma unroll
            for (int mi = 0; mi < 4; ++mi)
                acc[mi][ni] = MFMA_H(ah[mi], bf, acc[mi][ni], 0, 0, 0);
        }
    }

    #pragma unroll
    for (int mi = 0; mi < 4; ++mi) {
        #pragma unroll
        for (int r = 0; r < 4; ++r) {
            int gr = m0 + wm + mi * 16 + quad * 4 + r;
            if (gr >= 12608) continue;
            int bb = gr / 197;
            int ii = gr - bb * 197;
            #pragma unroll
            for (int ni = 0; ni < 4; ++ni) {
                int gc = n0 + wn + ni * 16 + l16;
                float val = acc[mi][ni][r] + bias[gc];
                if (kind == 1) {
                    outf[(size_t)gr * 768 + gc] = val;
                } else {
                    int h = gc >> 6, d = gc & 63;
                    if (z == 2) {
                        vtp[((size_t)(bb * 12 + h) * 64 + d) * 288 + ii] = f2h(val);
                    } else {
                        u16* O = z ? ko : qo;
                        O[((size_t)(bb * 12 + h) * 197 + ii) * 64 + d] = f2h(val);
                    }
                }
            }
        }
    }
}

// ---------------------------------------------------------------------------
// Fused attention, single-pass f16 MFMA, register-resident scores.
// Per block (qtile64, bh), 512 thr, 8 waves (mf=w>>1 rows, nh=w&1 col-half).
// Phase 0: Tvh = Q.Tk^T (frags direct from global) -> LDS fp32.
// Phase 1: S = Q.K^T (K frags direct from global) -> registers.
// In-register bias+scale; cross-wave softmax partials via red[]; unnorm p ->
// Ph f16. Hist phase -> Wv/Wh cols 208..271. Phase 2: O = Ph @ vt^T (K=288),
// scaled by 1/rowsum in epilogue; f16 output for the proj GEMM.
// LDS: Ph 64x296 u16 (37.9KB) + Tvh 64x68 f32 (17.4KB) + red 1KB -> 2 blk/CU.
// ---------------------------------------------------------------------------
__global__ __launch_bounds__(512, 4) void attn_mfma(
    const u16* __restrict__ qh, const u16* __restrict__ kh,
    const u16* __restrict__ tk, const u16* __restrict__ vt,
    u16* __restrict__ oh)
{
    __shared__ u16 Ph[64 * 296];
    __shared__ float Tvh[64 * 68];
    __shared__ float red[64 * 4];   // [m][max0,max1,sum0,sum1]

    const int qt = blockIdx.x, bh = blockIdx.y;
    const int I0 = qt * 64;
    const int tid = threadIdx.x;
    const int w = tid >> 6, lane = tid & 63, quad = lane >> 4, l16 = lane & 15;
    const int mf = w >> 1, nh = w & 1;
    const int mr0 = mf * 16;
    const size_t base = (size_t)bh * 197 * 64;
    const uint4 z4 = make_uint4(0, 0, 0, 0);

    // ---- Q A-frags direct from global (zero for i >= 197)
    half8 qa[2];
    {
        int i = I0 + mr0 + l16;
        bool ok = i < 197;
        const u16* qp = qh + base + (size_t)i * 64 + quad * 8;
        #pragma unroll
        for (int kb = 0; kb < 2; ++kb) {
            uint4 a = ok ? *(const uint4*)(qp + kb * 32) : z4;
            *(uint4*)&qa[kb] = a;
        }
    }

    // ---- phase 0: Tvh (cols nh*32 .. nh*32+31)
    #pragma unroll
    for (int s2 = 0; s2 < 2; ++s2) {
        int c = (nh * 2 + s2) * 16 + l16;
        f32x4 acc = (f32x4){0, 0, 0, 0};
        #pragma unroll
        for (int kb = 0; kb < 2; ++kb) {
            half8 th = ld_h8(tk + c * 64 + kb * 32 + quad * 8);
            acc = MFMA_H(qa[kb], th, acc, 0, 0, 0);
        }
        #pragma unroll
        for (int r = 0; r < 4; ++r)
            Tvh[(mr0 + quad * 4 + r) * 68 + c] = acc[r];
    }

    // ---- phase 1: S = Q.K^T (7 n-frags; nh=1's last frag void)
    f32x4 sacc[7];
    #pragma unroll
    for (int s = 0; s < 7; ++s) sacc[s] = (f32x4){0, 0, 0, 0};
    #pragma unroll
    for (int s = 0; s < 7; ++s) {
        int j = (nh * 7 + s) * 16 + l16;
        bool ok = j < 197;
        const u16* kp = kh + base + (size_t)j * 64 + quad * 8;
        f32x4 c = sacc[s];
        #pragma unroll
        for (int kb = 0; kb < 2; ++kb) {
            uint4 a = ok ? *(const uint4*)(kp + kb * 32) : z4;
            half8 kf; *(uint4*)&kf = a;
            c = MFMA_H(qa[kb], kf, c, 0, 0, 0);
        }
        sacc[s] = c;
    }
    __syncthreads();   // Tvh visible

    // ---- in-register bias + scale
    float sval[7][4];
    int jj[7];
    #pragma unroll
    for (int s = 0; s < 7; ++s) jj[s] = (nh * 7 + s) * 16 + l16;
    int ivA[4], ihA[4], iA[4];
    #pragma unroll
    for (int r = 0; r < 4; ++r) {
        int i = I0 + mr0 + quad * 4 + r;
        int qi = i - 1;
        int iv = qi / 14;
        ivA[r] = iv; ihA[r] = qi - iv * 14; iA[r] = i;
    }
    #pragma unroll
    for (int s = 0; s < 7; ++s) {
        int j = jj[s];
        if (j < 197) {
            int kj = j - 1;
            int jv = kj / 14;
            int jh2 = kj - jv * 14;
            #pragma unroll
            for (int r = 0; r < 4; ++r) {
                int m = mr0 + quad * 4 + r;
                int fv = 0, fh = 0;
                if (iA[r] > 0 && j > 0) {
                    int dv = jv - ivA[r]; dv = min(14, max(-14, dv));
                    int dh = jh2 - ihA[r]; dh = min(14, max(-14, dh));
                    fv = dv + 15; fh = dh + 15;
                }
                sval[s][r] = (sacc[s][r] + Tvh[m * 68 + fv] + Tvh[m * 68 + 32 + fh]) * SCALE_;
            }
        } else {
            #pragma unroll
            for (int r = 0; r < 4; ++r) sval[s][r] = -1e30f;
        }
    }

    // ---- partial row max -> red
    #pragma unroll
    for (int r = 0; r < 4; ++r) {
        float mx = sval[0][r];
        #pragma unroll
        for (int s = 1; s < 7; ++s) mx = fmaxf(mx, sval[s][r]);
        #pragma unroll
        for (int off = 1; off < 16; off <<= 1) mx = fmaxf(mx, __shfl_xor(mx, off, 64));
        if (l16 == 0) red[(mr0 + quad * 4 + r) * 4 + nh] = mx;
    }
    __syncthreads();

    // ---- exp + partial sums + write Ph (unnormalized p)
    #pragma unroll
    for (int r = 0; r < 4; ++r) {
        int m = mr0 + quad * 4 + r;
        float M = fmaxf(red[m * 4], red[m * 4 + 1]);
        float sum = 0.f;
        #pragma unroll
        for (int s = 0; s < 7; ++s) {
            float p = (jj[s] < 197) ? __expf(sval[s][r] - M) : 0.f;
            sval[s][r] = p;
            sum += p;
        }
        #pragma unroll
        for (int off = 1; off < 16; off <<= 1) sum += __shfl_xor(sum, off, 64);
        if (l16 == 0) red[m * 4 + 2 + nh] = sum;
    }
    #pragma unroll
    for (int s = 0; s < 7; ++s) {
        int j = jj[s];
        if (j < 208) {
            #pragma unroll
            for (int r = 0; r < 4; ++r)
                Ph[(mr0 + quad * 4 + r) * 296 + j] = f2h(sval[s][r]);
        }
    }
    __syncthreads();   // p cols + sums ready

    // ---- histogram phase: wave w owns rows w*8..w*8+7
    for (int q8 = 0; q8 < 8; ++q8) {
        int m = w * 8 + q8;
        int i = I0 + m;
        float bs = 0.f;
        if (lane < 14) {
            #pragma unroll
            for (int c = 0; c < 14; ++c) bs += h2f(Ph[m * 296 + 1 + lane * 14 + c]);
        } else if (lane >= 16 && lane < 30) {
            int c = lane - 16;
            #pragma unroll
            for (int b = 0; b < 14; ++b) bs += h2f(Ph[m * 296 + 1 + b * 14 + c]);
        }
        float pcls = h2f(Ph[m * 296]);
        float val;
        if (i == 0) {
            float lsum = red[m * 4 + 2] + red[m * 4 + 3];
            val = ((lane & 31) == 0) ? lsum : 0.f;
        } else {
            int qi = i - 1;
            int iv = qi / 14, ih = qi - (qi / 14) * 14;
            int r = lane & 31;
            int bidx = (lane < 32) ? (r + iv - 15) : (r + ih - 15);
            bool ok = (bidx >= 0) && (bidx <= 13) && (r < 30);
            int src = (lane < 32) ? min(13, max(0, bidx)) : 16 + min(13, max(0, bidx));
            float g = __shfl(bs, src, 64);
            val = ok ? g : 0.f;
            if (r == 0) val += pcls;
        }
        int col = (lane < 32) ? (208 + lane) : (240 + (lane - 32));
        Ph[m * 296 + col] = f2h(val);
    }
    // zero pad cols 272..287
    for (int t = tid; t < 64 * 16; t += 512)
        Ph[(t >> 4) * 296 + 272 + (t & 15)] = 0;
    __syncthreads();   // Ph complete

    // ---- phase 2: O = Ph @ vt^T (K=288), B-frags from global
    {
        f32x4 oacc[2] = {(f32x4){0, 0, 0, 0}, (f32x4){0, 0, 0, 0}};
        const u16* vb = vt + (size_t)bh * 64 * 288;
        #pragma unroll
        for (int ks = 0; ks < 9; ++ks) {
            half8 ap = ld_h8(&Ph[(mr0 + l16) * 296 + ks * 32 + quad * 8]);
            #pragma unroll
            for (int sd = 0; sd < 2; ++sd) {
                int d = (nh * 2 + sd) * 16 + l16;
                half8 bv = ld_h8(vb + (size_t)d * 288 + ks * 32 + quad * 8);
                oacc[sd] = MFMA_H(ap, bv, oacc[sd], 0, 0, 0);
            }
        }
        int b = bh / 12, h = bh - b * 12;
        float rl[4];
        #pragma unroll
        for (int r = 0; r < 4; ++r) {
            int m = mr0 + quad * 4 + r;
            rl[r] = 1.f / (red[m * 4 + 2] + red[m * 4 + 3]);
        }
        #pragma unroll
        for (int sd = 0; sd < 2; ++sd) {
            int d = (nh * 2 + sd) * 16 + l16;
            #pragma unroll
            for (int r = 0; r < 4; ++r) {
                int i = I0 + mr0 + quad * 4 + r;
                if (i < 197) {
                    oh[((size_t)(b * 197 + i)) * 768 + h * 64 + d] =
                        f2h(oacc[sd][r] * rl[r]);
                }
            }
        }
    }
}

// ---------------------------------------------------------------------------
extern "C" void kernel_launch(void* const* d_in, const int* in_sizes, int n_in,
                              void* d_out, int out_size, void* d_ws, size_t ws_size,
                              hipStream_t stream)
{
    const float* x   = (const float*)d_in[0];
    const float* wq  = (const float*)d_in[1];
    const float* bq  = (const float*)d_in[2];
    const float* wk  = (const float*)d_in[3];
    const float* bk  = (const float*)d_in[4];
    const float* wv  = (const float*)d_in[5];
    const float* bv  = (const float*)d_in[6];
    const float* wp  = (const float*)d_in[7];
    const float* bp  = (const float*)d_in[8];
    const float* rkv = (const float*)d_in[9];
    const float* rkh = (const float*)d_in[10];
    const float* rvv = (const float*)d_in[11];
    const float* rvh = (const float*)d_in[12];
    float* out = (float*)d_out;

    const size_t SZX = (size_t)12608 * 768;
    const size_t SZW = (size_t)768 * 768;
    const size_t SZVT = (size_t)768 * 64 * 288;

    u16* xh = (u16*)d_ws;
    u16* qh_ = xh + SZX;
    u16* kh_ = qh_ + SZX;
    u16* vt  = kh_ + SZX;
    u16* wt  = vt + SZVT;
    u16* wqh = wt;
    u16* wkh = wt + SZW;
    u16* wvh = wt + 2 * SZW;
    u16* wph = wt + 3 * SZW;
    u16* tk  = wt + 4 * SZW;
    u16* rth = tk + 4096;
    u16* oh_ = xh;   // overlay: x dead after QKV projection

    prep_half_x<<<4728, 256, 0, stream>>>(x, xh);
    prep_w<<<dim3(12, 12, 4), 256, 0, stream>>>(wq, wk, wv, wp, wqh, wkh, wvh, wph);
    prep_tabs<<<1, 256, 0, stream>>>(rkv, rkh, rvv, rvh, tk, rth);
    prep_vt<<<768, 256, 0, stream>>>(rth, vt);

    gemm_f16<<<dim3(6, 99, 3), 256, 0, stream>>>(
        xh, wqh, wkh, wvh, bq, bk, bv, qh_, kh_, vt, nullptr, 0);

    attn_mfma<<<dim3(4, 768), 512, 0, stream>>>(qh_, kh_, tk, vt, oh_);

    gemm_f16<<<dim3(6, 99, 1), 256, 0, stream>>>(
        oh_, wph, wph, wph, bp, bp, bp, nullptr, nullptr, nullptr, out, 1);
}

// Round 6
// 331.896 us; speedup vs baseline: 9.5217x; 1.2003x over previous
//
#include <hip/hip_runtime.h>
#include <math.h>

#define SCALE_ 0.125f

typedef unsigned short u16;
typedef __attribute__((ext_vector_type(8))) _Float16 half8;
typedef __attribute__((ext_vector_type(4))) float f32x4;
#define MFMA_H __builtin_amdgcn_mfma_f32_16x16x32_f16

__device__ __forceinline__ u16 f2h(float f) {
    union { _Float16 h; u16 u; } v; v.h = (_Float16)f; return v.u;
}
__device__ __forceinline__ float h2f(u16 u) {
    union { _Float16 h; u16 u; } v; v.u = u; return (float)v.h;
}
__device__ __forceinline__ void gload16(const u16* g, u16* l) {
    __builtin_amdgcn_global_load_lds(
        (const __attribute__((address_space(1))) void*)g,
        (__attribute__((address_space(3))) void*)l, 16, 0, 0);
}
__device__ __forceinline__ half8 ld_h8(const u16* p) {
    return *(const half8*)p;
}

// ---------------------------------------------------------------------------
// prep: x -> f16
// ---------------------------------------------------------------------------
__global__ void prep_half_x(const float* __restrict__ x, u16* __restrict__ xh) {
    size_t idx = ((size_t)blockIdx.x * 256 + threadIdx.x) * 8;
    float4 a = *(const float4*)(x + idx), b = *(const float4*)(x + idx + 4);
    float f[8] = {a.x, a.y, a.z, a.w, b.x, b.y, b.z, b.w};
    u16 hs[8];
    #pragma unroll
    for (int e = 0; e < 8; ++e) hs[e] = f2h(f[e]);
    *(uint4*)(xh + idx) = *(uint4*)hs;
}

// ---------------------------------------------------------------------------
// prep: transpose weights: Wt[n][k] = W[k][n], f16
// ---------------------------------------------------------------------------
__global__ void prep_w(const float* __restrict__ w0, const float* __restrict__ w1,
                       const float* __restrict__ w2, const float* __restrict__ w3,
                       u16* o0, u16* o1, u16* o2, u16* o3) {
    const float* W; u16* oh;
    if (blockIdx.z == 0)      { W = w0; oh = o0; }
    else if (blockIdx.z == 1) { W = w1; oh = o1; }
    else if (blockIdx.z == 2) { W = w2; oh = o2; }
    else                      { W = w3; oh = o3; }

    __shared__ float t[64 * 68];
    int k0 = blockIdx.y * 64, n0 = blockIdx.x * 64;
    int tid = threadIdx.x;
    #pragma unroll
    for (int rr = 0; rr < 4; ++rr) {
        int r = (tid >> 4) + rr * 16;
        int c = (tid & 15) * 4;
        *(float4*)&t[r * 68 + c] = *(const float4*)(W + (size_t)(k0 + r) * 768 + n0 + c);
    }
    __syncthreads();
    int n = tid >> 2, kc = (tid & 3) * 16;
    u16 hs[16];
    #pragma unroll
    for (int e = 0; e < 16; ++e) hs[e] = f2h(t[(kc + e) * 68 + n]);
    size_t o = (size_t)(n0 + n) * 768 + k0 + kc;
    *(uint4*)(oh + o) = *(uint4*)hs;
    *(uint4*)(oh + o + 8) = *(uint4*)(hs + 8);
}

// ---------------------------------------------------------------------------
// prep: tables. tk[r][d] f16 (r: 0..29 rkv, 32..61 rkh, zeros elsewhere);
// rth[d][r] = rel_v tables transposed, f16.
// ---------------------------------------------------------------------------
__global__ void prep_tabs(const float* __restrict__ rkv, const float* __restrict__ rkh,
                          const float* __restrict__ rvv, const float* __restrict__ rvh,
                          u16* tk, u16* rth) {
    for (int idx = threadIdx.x; idx < 4096; idx += 256) {
        int r = idx >> 6, d = idx & 63;
        float tv = 0.f;
        if (r < 30) tv = rkv[r * 64 + d];
        else if (r >= 32 && r < 62) tv = rkh[(r - 32) * 64 + d];
        tk[idx] = f2h(tv);
        int dd = idx >> 6, rr = idx & 63;
        float vv = 0.f;
        if (rr < 30) vv = rvv[rr * 64 + dd];
        else if (rr >= 32 && rr < 62) vv = rvh[(rr - 32) * 64 + dd];
        rth[idx] = f2h(vv);
    }
}

// ---------------------------------------------------------------------------
// prep: constant part of vt[bh][d][288]: cols 197..207 zero, 208..271 rel_v
// ([d][r] from rth), 272..287 zero. (cols 0..196 from vtrans.)
// ---------------------------------------------------------------------------
__global__ void prep_vt(const u16* __restrict__ rth, u16* __restrict__ vtp) {
    u16* vb = vtp + (size_t)blockIdx.x * 64 * 288;
    for (int t = threadIdx.x; t < 64 * 91; t += 256) {
        int d = t / 91;
        int c = 197 + (t - d * 91);
        u16 val = 0;
        if (c >= 208 && c < 272) val = rth[d * 64 + (c - 208)];
        vb[d * 288 + c] = val;
    }
}

// ---------------------------------------------------------------------------
// transpose v (bh,key,d) -> vt[bh][d][288] cols 0..196 (key-major)
// ---------------------------------------------------------------------------
__global__ __launch_bounds__(256) void vtrans(const u16* __restrict__ v,
                                              u16* __restrict__ vt) {
    __shared__ u16 L[64 * 72];
    const int bh = blockIdx.x;
    const u16* src = v + (size_t)bh * 197 * 64;
    u16* dst = vt + (size_t)bh * 64 * 288;
    const int tid = threadIdx.x;
    const int keyl = tid >> 2;
    const int c8 = (tid & 3) * 16;
    for (int k0 = 0; k0 < 197; k0 += 64) {
        __syncthreads();
        int key = k0 + keyl;
        if (key < 197) {
            uint4 g0 = *(const uint4*)(src + key * 64 + c8);
            uint4 g1 = *(const uint4*)(src + key * 64 + c8 + 8);
            u16 t0[8]; *(uint4*)t0 = g0;
            u16 t1[8]; *(uint4*)t1 = g1;
            #pragma unroll
            for (int e = 0; e < 8; ++e) L[(c8 + e) * 72 + keyl] = t0[e];
            #pragma unroll
            for (int e = 0; e < 8; ++e) L[(c8 + 8 + e) * 72 + keyl] = t1[e];
        }
        __syncthreads();
        int d = tid >> 2, cc = (tid & 3) * 16;
        if (k0 + cc < 197) {
            int nvalid = min(16, 197 - k0 - cc);
            if (nvalid == 16) {
                *(uint4*)(dst + d * 288 + k0 + cc)     = *(const uint4*)&L[d * 72 + cc];
                *(uint4*)(dst + d * 288 + k0 + cc + 8) = *(const uint4*)&L[d * 72 + cc + 8];
            } else {
                for (int e = 0; e < nvalid; ++e)
                    dst[d * 288 + k0 + cc + e] = L[d * 72 + cc + e];
            }
        }
    }
}

// ---------------------------------------------------------------------------
// Single-pass f16 MFMA GEMM, XCD-grouped work mapping, BK=64, LDS-bounce
// epilogue. C(12608,768) = A @ B + bias; A f16 row-major, B as Bt[n][k] f16.
// Work map: xcd = blockIdx%8 owns a contiguous m-range; its 6*nz (n,z) blocks
// per m run temporally adjacent on that XCD -> A-tile stays in its L2.
// kind 0 (QKV): z=0/1/2 -> q/k/v scatter (B,H,N,64) u16 via LDS bounce.
// kind 1 (proj): plain fp32 output.
// ---------------------------------------------------------------------------
__global__ __launch_bounds__(256, 4) void gemm_f16(
    const u16* __restrict__ Ah,
    const u16* __restrict__ B0, const u16* __restrict__ B1, const u16* __restrict__ B2,
    const float* __restrict__ bias0, const float* __restrict__ bias1,
    const float* __restrict__ bias2,
    u16* qo, u16* ko, u16* vo, float* outf, int nz, int kind)
{
    __shared__ u16 SM[128 * 64 * 2];
    u16* As = SM;
    u16* Bs = SM + 128 * 64;

    const int p = blockIdx.x;
    const int xcd = p & 7, s = p >> 3;
    const int mcnt = (xcd < 3) ? 13 : 12;
    const int mbase = (xcd < 3) ? xcd * 13 : 39 + (xcd - 3) * 12;
    const int jn = 6 * nz;
    if (s >= mcnt * jn) return;
    const int mb = mbase + s / jn;
    const int j = s % jn;
    const int z = j / 6;
    const int nb = j % 6;

    const u16* Bt = B0; const float* bias = bias0;
    if (z == 1) { Bt = B1; bias = bias1; }
    else if (z == 2) { Bt = B2; bias = bias2; }

    const int m0 = mb * 128, n0 = nb * 128;
    const int tid = threadIdx.x;
    const int w = tid >> 6, lane = tid & 63, quad = lane >> 4, l16 = lane & 15;
    const int wm = (w >> 1) * 64, wn = (w & 1) * 64;
    const int rl8 = lane >> 3, cs = lane & 7;
    const int csrc = (cs ^ rl8) * 8;

    f32x4 acc[4][4];
    #pragma unroll
    for (int a = 0; a < 4; ++a)
        #pragma unroll
        for (int b = 0; b < 4; ++b) acc[a][b] = (f32x4){0, 0, 0, 0};

    for (int kt = 0; kt < 768; kt += 64) {
        __syncthreads();
        #pragma unroll
        for (int i = 0; i < 4; ++i) {
            int r = w * 32 + i * 8 + rl8;
            int arow = min(m0 + r, 12607);
            gload16(Ah + (size_t)arow * 768 + kt + csrc, &As[(w * 32 + i * 8) * 64]);
            gload16(Bt + (size_t)(n0 + r) * 768 + kt + csrc, &Bs[(w * 32 + i * 8) * 64]);
        }
        __syncthreads();
        #pragma unroll
        for (int kb = 0; kb < 2; ++kb) {
            const int slot = ((kb * 4 + quad) ^ (l16 & 7)) * 8;
            half8 ah[4], bf[4];
            #pragma unroll
            for (int mi = 0; mi < 4; ++mi) {
                ah[mi] = ld_h8(&As[(wm + mi * 16 + l16) * 64 + slot]);
                bf[mi] = ld_h8(&Bs[(wn + mi * 16 + l16) * 64 + slot]);
            }
            #pragma unroll
            for (int ni = 0; ni < 4; ++ni)
                #pragma unroll
                for (int mi = 0; mi < 4; ++mi)
                    acc[mi][ni] = MFMA_H(ah[mi], bf[ni], acc[mi][ni], 0, 0, 0);
        }
    }

    if (kind == 1) {
        #pragma unroll
        for (int mi = 0; mi < 4; ++mi) {
            #pragma unroll
            for (int r = 0; r < 4; ++r) {
                int gr = m0 + wm + mi * 16 + quad * 4 + r;
                if (gr >= 12608) continue;
                #pragma unroll
                for (int ni = 0; ni < 4; ++ni) {
                    int gc = n0 + wn + ni * 16 + l16;
                    outf[(size_t)gr * 768 + gc] = acc[mi][ni][r] + bias[gc];
                }
            }
        }
        return;
    }

    // ---- LDS-bounce epilogue: Cs[128][128] u16 (overlays As/Bs)
    __syncthreads();
    u16* Cs = SM;
    #pragma unroll
    for (int mi = 0; mi < 4; ++mi) {
        #pragma unroll
        for (int ni = 0; ni < 4; ++ni) {
            int col = wn + ni * 16 + l16;
            float bv = bias[n0 + col];
            #pragma unroll
            for (int r = 0; r < 4; ++r)
                Cs[(wm + mi * 16 + quad * 4 + r) * 128 + col] = f2h(acc[mi][ni][r] + bv);
        }
    }
    __syncthreads();
    u16* O = (z == 0) ? qo : ((z == 1) ? ko : vo);
    int row = tid >> 1, halfc = tid & 1;
    int gr = m0 + row;
    if (gr < 12608) {
        int bb = gr / 197, ii = gr - bb * 197;
        int h = (n0 >> 6) + halfc;
        u16* dst = O + ((size_t)(bb * 12 + h) * 197 + ii) * 64;
        const u16* src = &Cs[row * 128 + halfc * 64];
        #pragma unroll
        for (int e = 0; e < 8; ++e)
            *(uint4*)(dst + e * 8) = *(const uint4*)(src + e * 8);
    }
}

// ---------------------------------------------------------------------------
// Fused attention, single-pass f16 MFMA, register-resident scores.
// XCD-grouped: 4 qt-blocks of one bh run adjacent on one XCD.
// ---------------------------------------------------------------------------
__global__ __launch_bounds__(512, 4) void attn_mfma(
    const u16* __restrict__ qh, const u16* __restrict__ kh,
    const u16* __restrict__ tk, const u16* __restrict__ vt,
    u16* __restrict__ oh)
{
    __shared__ u16 Ph[64 * 296];
    __shared__ float Tvh[64 * 68];
    __shared__ float red[64 * 4];   // [m][max0,max1,sum0,sum1]

    const int p = blockIdx.x;
    const int xcd = p & 7, s = p >> 3;
    const int bh = xcd * 96 + (s >> 2);
    const int qt = s & 3;
    const int I0 = qt * 64;
    const int tid = threadIdx.x;
    const int w = tid >> 6, lane = tid & 63, quad = lane >> 4, l16 = lane & 15;
    const int mf = w >> 1, nh = w & 1;
    const int mr0 = mf * 16;
    const size_t base = (size_t)bh * 197 * 64;
    const uint4 z4 = make_uint4(0, 0, 0, 0);

    // ---- Q A-frags direct from global (zero for i >= 197)
    half8 qa[2];
    {
        int i = I0 + mr0 + l16;
        bool ok = i < 197;
        const u16* qp = qh + base + (size_t)i * 64 + quad * 8;
        #pragma unroll
        for (int kb = 0; kb < 2; ++kb) {
            uint4 a = ok ? *(const uint4*)(qp + kb * 32) : z4;
            *(uint4*)&qa[kb] = a;
        }
    }

    // ---- phase 0: Tvh (cols nh*32 .. nh*32+31)
    #pragma unroll
    for (int s2 = 0; s2 < 2; ++s2) {
        int c = (nh * 2 + s2) * 16 + l16;
        f32x4 acc = (f32x4){0, 0, 0, 0};
        #pragma unroll
        for (int kb = 0; kb < 2; ++kb) {
            half8 th = ld_h8(tk + c * 64 + kb * 32 + quad * 8);
            acc = MFMA_H(qa[kb], th, acc, 0, 0, 0);
        }
        #pragma unroll
        for (int r = 0; r < 4; ++r)
            Tvh[(mr0 + quad * 4 + r) * 68 + c] = acc[r];
    }

    // ---- phase 1: S = Q.K^T (7 n-frags; nh=1's last frag void)
    f32x4 sacc[7];
    #pragma unroll
    for (int s1 = 0; s1 < 7; ++s1) sacc[s1] = (f32x4){0, 0, 0, 0};
    #pragma unroll
    for (int s1 = 0; s1 < 7; ++s1) {
        int j = (nh * 7 + s1) * 16 + l16;
        bool ok = j < 197;
        const u16* kp = kh + base + (size_t)j * 64 + quad * 8;
        f32x4 c = sacc[s1];
        #pragma unroll
        for (int kb = 0; kb < 2; ++kb) {
            uint4 a = ok ? *(const uint4*)(kp + kb * 32) : z4;
            half8 kf; *(uint4*)&kf = a;
            c = MFMA_H(qa[kb], kf, c, 0, 0, 0);
        }
        sacc[s1] = c;
    }
    __syncthreads();   // Tvh visible

    // ---- in-register bias + scale
    float sval[7][4];
    int jj[7];
    #pragma unroll
    for (int s1 = 0; s1 < 7; ++s1) jj[s1] = (nh * 7 + s1) * 16 + l16;
    int ivA[4], ihA[4], iA[4];
    #pragma unroll
    for (int r = 0; r < 4; ++r) {
        int i = I0 + mr0 + quad * 4 + r;
        int qi = i - 1;
        int iv = qi / 14;
        ivA[r] = iv; ihA[r] = qi - iv * 14; iA[r] = i;
    }
    #pragma unroll
    for (int s1 = 0; s1 < 7; ++s1) {
        int j = jj[s1];
        if (j < 197) {
            int kj = j - 1;
            int jv = kj / 14;
            int jh2 = kj - jv * 14;
            #pragma unroll
            for (int r = 0; r < 4; ++r) {
                int m = mr0 + quad * 4 + r;
                int fv = 0, fh = 0;
                if (iA[r] > 0 && j > 0) {
                    int dv = jv - ivA[r]; dv = min(14, max(-14, dv));
                    int dh = jh2 - ihA[r]; dh = min(14, max(-14, dh));
                    fv = dv + 15; fh = dh + 15;
                }
                sval[s1][r] = (sacc[s1][r] + Tvh[m * 68 + fv] + Tvh[m * 68 + 32 + fh]) * SCALE_;
            }
        } else {
            #pragma unroll
            for (int r = 0; r < 4; ++r) sval[s1][r] = -1e30f;
        }
    }

    // ---- partial row max -> red
    #pragma unroll
    for (int r = 0; r < 4; ++r) {
        float mx = sval[0][r];
        #pragma unroll
        for (int s1 = 1; s1 < 7; ++s1) mx = fmaxf(mx, sval[s1][r]);
        #pragma unroll
        for (int off = 1; off < 16; off <<= 1) mx = fmaxf(mx, __shfl_xor(mx, off, 64));
        if (l16 == 0) red[(mr0 + quad * 4 + r) * 4 + nh] = mx;
    }
    __syncthreads();

    // ---- exp + partial sums + write Ph (unnormalized p)
    #pragma unroll
    for (int r = 0; r < 4; ++r) {
        int m = mr0 + quad * 4 + r;
        float M = fmaxf(red[m * 4], red[m * 4 + 1]);
        float sum = 0.f;
        #pragma unroll
        for (int s1 = 0; s1 < 7; ++s1) {
            float pv = (jj[s1] < 197) ? __expf(sval[s1][r] - M) : 0.f;
            sval[s1][r] = pv;
            sum += pv;
        }
        #pragma unroll
        for (int off = 1; off < 16; off <<= 1) sum += __shfl_xor(sum, off, 64);
        if (l16 == 0) red[m * 4 + 2 + nh] = sum;
    }
    #pragma unroll
    for (int s1 = 0; s1 < 7; ++s1) {
        int j = jj[s1];
        if (j < 208) {
            #pragma unroll
            for (int r = 0; r < 4; ++r)
                Ph[(mr0 + quad * 4 + r) * 296 + j] = f2h(sval[s1][r]);
        }
    }
    __syncthreads();   // p cols + sums ready

    // ---- histogram phase: wave w owns rows w*8..w*8+7
    for (int q8 = 0; q8 < 8; ++q8) {
        int m = w * 8 + q8;
        int i = I0 + m;
        float bs = 0.f;
        if (lane < 14) {
            #pragma unroll
            for (int c = 0; c < 14; ++c) bs += h2f(Ph[m * 296 + 1 + lane * 14 + c]);
        } else if (lane >= 16 && lane < 30) {
            int c = lane - 16;
            #pragma unroll
            for (int b = 0; b < 14; ++b) bs += h2f(Ph[m * 296 + 1 + b * 14 + c]);
        }
        float pcls = h2f(Ph[m * 296]);
        float val;
        if (i == 0) {
            float lsum = red[m * 4 + 2] + red[m * 4 + 3];
            val = ((lane & 31) == 0) ? lsum : 0.f;
        } else {
            int qi = i - 1;
            int iv = qi / 14, ih = qi - (qi / 14) * 14;
            int r = lane & 31;
            int bidx = (lane < 32) ? (r + iv - 15) : (r + ih - 15);
            bool ok = (bidx >= 0) && (bidx <= 13) && (r < 30);
            int src = (lane < 32) ? min(13, max(0, bidx)) : 16 + min(13, max(0, bidx));
            float g = __shfl(bs, src, 64);
            val = ok ? g : 0.f;
            if (r == 0) val += pcls;
        }
        int col = (lane < 32) ? (208 + lane) : (240 + (lane - 32));
        Ph[m * 296 + col] = f2h(val);
    }
    // zero pad cols 272..287
    for (int t = tid; t < 64 * 16; t += 512)
        Ph[(t >> 4) * 296 + 272 + (t & 15)] = 0;
    __syncthreads();   // Ph complete

    // ---- phase 2: O = Ph @ vt^T (K=288), B-frags from global
    {
        f32x4 oacc[2] = {(f32x4){0, 0, 0, 0}, (f32x4){0, 0, 0, 0}};
        const u16* vb = vt + (size_t)bh * 64 * 288;
        #pragma unroll
        for (int ks = 0; ks < 9; ++ks) {
            half8 ap = ld_h8(&Ph[(mr0 + l16) * 296 + ks * 32 + quad * 8]);
            #pragma unroll
            for (int sd = 0; sd < 2; ++sd) {
                int d = (nh * 2 + sd) * 16 + l16;
                half8 bv = ld_h8(vb + (size_t)d * 288 + ks * 32 + quad * 8);
                oacc[sd] = MFMA_H(ap, bv, oacc[sd], 0, 0, 0);
            }
        }
        int b = bh / 12, h = bh - b * 12;
        float rl[4];
        #pragma unroll
        for (int r = 0; r < 4; ++r) {
            int m = mr0 + quad * 4 + r;
            rl[r] = 1.f / (red[m * 4 + 2] + red[m * 4 + 3]);
        }
        #pragma unroll
        for (int sd = 0; sd < 2; ++sd) {
            int d = (nh * 2 + sd) * 16 + l16;
            #pragma unroll
            for (int r = 0; r < 4; ++r) {
                int i = I0 + mr0 + quad * 4 + r;
                if (i < 197) {
                    oh[((size_t)(b * 197 + i)) * 768 + h * 64 + d] =
                        f2h(oacc[sd][r] * rl[r]);
                }
            }
        }
    }
}

// ---------------------------------------------------------------------------
extern "C" void kernel_launch(void* const* d_in, const int* in_sizes, int n_in,
                              void* d_out, int out_size, void* d_ws, size_t ws_size,
                              hipStream_t stream)
{
    const float* x   = (const float*)d_in[0];
    const float* wq  = (const float*)d_in[1];
    const float* bq  = (const float*)d_in[2];
    const float* wk  = (const float*)d_in[3];
    const float* bk  = (const float*)d_in[4];
    const float* wv  = (const float*)d_in[5];
    const float* bv  = (const float*)d_in[6];
    const float* wp  = (const float*)d_in[7];
    const float* bp  = (const float*)d_in[8];
    const float* rkv = (const float*)d_in[9];
    const float* rkh = (const float*)d_in[10];
    const float* rvv = (const float*)d_in[11];
    const float* rvh = (const float*)d_in[12];
    float* out = (float*)d_out;

    const size_t SZX = (size_t)12608 * 768;
    const size_t SZW = (size_t)768 * 768;
    const size_t SZVT = (size_t)768 * 64 * 288;

    u16* xh  = (u16*)d_ws;
    u16* qh_ = xh + SZX;
    u16* kh_ = qh_ + SZX;
    u16* vh_ = kh_ + SZX;
    u16* vt  = vh_ + SZX;
    u16* wt  = vt + SZVT;
    u16* wqh = wt;
    u16* wkh = wt + SZW;
    u16* wvh = wt + 2 * SZW;
    u16* wph = wt + 3 * SZW;
    u16* tk  = wt + 4 * SZW;
    u16* rth = tk + 4096;
    u16* oh_ = xh;   // overlay: x dead after QKV projection

    prep_half_x<<<4728, 256, 0, stream>>>(x, xh);
    prep_w<<<dim3(12, 12, 4), 256, 0, stream>>>(wq, wk, wv, wp, wqh, wkh, wvh, wph);
    prep_tabs<<<1, 256, 0, stream>>>(rkv, rkh, rvv, rvh, tk, rth);
    prep_vt<<<768, 256, 0, stream>>>(rth, vt);

    // QKV: 8 XCDs * 13 m-slots * (6n * 3z) = 1872 blocks
    gemm_f16<<<1872, 256, 0, stream>>>(
        xh, wqh, wkh, wvh, bq, bk, bv, qh_, kh_, vh_, nullptr, 3, 0);

    vtrans<<<768, 256, 0, stream>>>(vh_, vt);

    attn_mfma<<<3072, 512, 0, stream>>>(qh_, kh_, tk, vt, oh_);

    // proj: 8 * 13 * 6 = 624 blocks
    gemm_f16<<<624, 256, 0, stream>>>(
        oh_, wph, wph, wph, bp, bp, bp, nullptr, nullptr, nullptr, out, 1, 1);
}